// Round 10
// baseline (708.372 us; speedup 1.0000x reference)
//
#include <hip/hip_runtime.h>
#include <math.h>

// ---------------------------------------------------------------------------
// Swin/Uformer block, MI355X. Sizes fixed: B=4 H=W=256 C=96 NH=3 HD=32 WIN=8
// N=64 HID=384. 3 kernels:
//   kwconv : f32 weights -> bf16 pre-swizzled B-frags; + wdw transposed f32
//   kattn  : LN1 + QKV + window-attn (+rpb bias, softmax) + proj + residual
//   kleff  : FUSED LN2+FC1+GELU+dwconv3x3+GELU+FC2+residual, channel-SIXTHS:
//            h kept as f32 in a 26.6KB LDS buffer (5 blocks/CU), conv math is
//            packed-f32 FMA (no bf16 unpack), dw weights stream from L1.
// MFMA 16x16x32 bf16 layouts used throughout:
//   A-frag: lane = (m%16) + 16*(k%32/8), elem = k%8
//   B-frag: lane = (n%16) + 16*(k%32/8), elem = k%8
//   C/D   : row  = 4*(lane/16)+reg, col = lane%16
// ---------------------------------------------------------------------------

typedef __attribute__((ext_vector_type(8))) short bf16x8;
typedef __attribute__((ext_vector_type(4))) float f32x4;

#define MFMA(a, b, c) __builtin_amdgcn_mfma_f32_16x16x32_bf16((a), (b), (c), 0, 0, 0)

// weight tile bases (in 16x32 B-fragment tiles of 64 lanes * 16B)
#define WQ_T 0
#define WKV_T 18
#define WP_T 54
#define W1_T 72
#define W2_T 144
#define NTILES_TOT 216

__device__ __forceinline__ unsigned short f2bf(float f) {
  union { float f; unsigned u; } v; v.f = f;
  unsigned r = v.u + 0x7FFFu + ((v.u >> 16) & 1u);
  return (unsigned short)(r >> 16);
}
__device__ __forceinline__ unsigned cvtpk_bf16(float lo, float hi) {
  unsigned r;
  asm("v_cvt_pk_bf16_f32 %0, %1, %2" : "=v"(r) : "v"(lo), "v"(hi));
  return r;
}
// gelu(x) = x * sigmoid(2z), z = 0.7978845608 x (1 + 0.044715 x^2)
__device__ __forceinline__ float gelu(float x) {
  float t = x * x;
  float w = x * fmaf(t, -0.07135941f, -1.5957691f);   // -2z
  float a = __expf(w);
  return x * __builtin_amdgcn_rcpf(1.f + a);
}
__device__ __forceinline__ bf16x8 ldw(const unsigned short* wswz, int tile, int lane) {
  return *(const bf16x8*)(wswz + ((size_t)(tile * 64 + lane)) * 8);
}
__device__ __forceinline__ int xcd_swz(int bid) {   // 4096 % 8 == 0 -> bijective
  return (bid & 7) * 512 + (bid >> 3);
}

// --------------------------- weight convert/swizzle ------------------------
__global__ void kwconv(const float* __restrict__ wq, const float* __restrict__ wkv,
                       const float* __restrict__ wp, const float* __restrict__ w1,
                       const float* __restrict__ w2, const float* __restrict__ wdw,
                       unsigned short* __restrict__ wswz, float* __restrict__ wdwT) {
  int tid = blockIdx.x * 256 + threadIdx.x;
  if (tid >= NTILES_TOT * 64) {
    int i = tid - NTILES_TOT * 64;
    if (i < 3456) {                       // wdw (384,1,3,3) -> wdwT [tap][384]
      int ch = i % 384, tap = i / 384;
      wdwT[tap * 384 + ch] = wdw[ch * 9 + tap];
    }
    return;
  }
  int e = tid; const float* src; int N, NT;
  if (e < 1152)      { src = wq;  N = 96;  NT = 6; }
  else if (e < 3456) { src = wkv; N = 192; NT = 12; e -= 1152; }
  else if (e < 4608) { src = wp;  N = 96;  NT = 6;  e -= 3456; }
  else if (e < 9216) { src = w1;  N = 384; NT = 24; e -= 4608; }
  else               { src = w2;  N = 96;  NT = 6;  e -= 9216; }
  int lane = e & 63, t = e >> 6;
  int nt = t % NT, kt = t / NT;
  int k0 = kt * 32 + (lane >> 4) * 8;
  int n = nt * 16 + (lane & 15);
  unsigned short* dst = wswz + (size_t)tid * 8;
#pragma unroll
  for (int i = 0; i < 8; ++i) dst[i] = f2bf(src[(size_t)(k0 + i) * N + n]);
}

// --------------------------- attention block -------------------------------
__global__ __launch_bounds__(256) void kattn(
    const float* __restrict__ x, const float* __restrict__ g1, const float* __restrict__ b1,
    const float* __restrict__ bq, const float* __restrict__ bkv,
    const float* __restrict__ rpb, const float* __restrict__ bp,
    const unsigned short* __restrict__ wswz, float* __restrict__ x2) {
  __shared__ __align__(16) unsigned short sm0[4 * 3 * 64 * 8];   // xn_swz, later y_swz (12KB)
  __shared__ __align__(16) unsigned short sm1[24 * 64 * 8];      // q(12 tiles)+k(12) then p(24) (24KB)
  __shared__ __align__(16) unsigned short sm2[3 * 2 * 2 * 64 * 8]; // v (12KB)

  const int tid = threadIdx.x;
  const int lane = tid & 63, w = tid >> 6;
  const int lrow = lane >> 4, lcol = lane & 15;
  const int wi = xcd_swz(blockIdx.x);
  const int b = wi >> 10, wy = (wi >> 5) & 31, wx = wi & 31;

  long rowoff[4];
#pragma unroll
  for (int r = 0; r < 4; ++r) {
    int m = w * 16 + lrow * 4 + r;
    int gy = wy * 8 + (m >> 3), gx = wx * 8 + (m & 7);
    rowoff[r] = ((long)b * 65536 + gy * 256 + gx) * 96;
  }

  // ---- phase 0: load x (C/D-layout regs), LN1, write xn to A-swz LDS
  float xv[4][6], xn[4][6], gv[6], bv[6];
#pragma unroll
  for (int nt = 0; nt < 6; ++nt) {
    int c = nt * 16 + lcol;
    gv[nt] = g1[c]; bv[nt] = b1[c];
#pragma unroll
    for (int r = 0; r < 4; ++r) xv[r][nt] = x[rowoff[r] + c];
  }
#pragma unroll
  for (int r = 0; r < 4; ++r) {
    float s = 0.f, sq = 0.f;
#pragma unroll
    for (int nt = 0; nt < 6; ++nt) { float v = xv[r][nt]; s += v; sq += v * v; }
#pragma unroll
    for (int off = 1; off <= 8; off <<= 1) { s += __shfl_xor(s, off, 64); sq += __shfl_xor(sq, off, 64); }
    float mean = s * (1.f / 96.f);
    float var = sq * (1.f / 96.f) - mean * mean;
    float rs = rsqrtf(var + 1e-5f);
#pragma unroll
    for (int nt = 0; nt < 6; ++nt) xn[r][nt] = (xv[r][nt] - mean) * rs * gv[nt] + bv[nt];
  }
#pragma unroll
  for (int r = 0; r < 4; ++r) {
    int mm = lrow * 4 + r;
#pragma unroll
    for (int nt = 0; nt < 6; ++nt) {
      int c = nt * 16 + lcol;
      int kt = c >> 5;
      int lanew = mm + (((c & 31) >> 3) << 4);
      sm0[((w * 3 + kt) * 64 + lanew) * 8 + (c & 7)] = f2bf(xn[r][nt]);
    }
  }
  __syncthreads();

  // ---- phase 1: QKV GEMM (M=64 N=288 K=96), wave w owns m-tile w
  bf16x8 af[3];
#pragma unroll
  for (int kt = 0; kt < 3; ++kt) af[kt] = *(const bf16x8*)(sm0 + ((w * 3 + kt) * 64 + lane) * 8);
  for (int nt = 0; nt < 18; ++nt) {
    f32x4 acc = {0.f, 0.f, 0.f, 0.f};
#pragma unroll
    for (int kt = 0; kt < 3; ++kt) {
      int tile = (nt < 6) ? (WQ_T + kt * 6 + nt) : (WKV_T + kt * 12 + (nt - 6));
      acc = MFMA(af[kt], ldw(wswz, tile, lane), acc);
    }
    int c = nt * 16 + lcol;
#pragma unroll
    for (int r = 0; r < 4; ++r) {
      int m = w * 16 + lrow * 4 + r;
      float val = acc[r];
      if (c < 96) {                 // q (pre-scaled)
        val = (val + bq[c]) * 0.17677669529663687f;
        int head = c >> 5, d = c & 31;
        sm1[((head * 4 + w) * 64 + (m & 15) + ((d >> 3) << 4)) * 8 + (d & 7)] = f2bf(val);
      } else if (c < 192) {         // k
        int kc = c - 96;
        val += bkv[kc];
        int head = kc >> 5, d = kc & 31;
        sm1[((12 + head * 4 + w) * 64 + (m & 15) + ((d >> 3) << 4)) * 8 + (d & 7)] = f2bf(val);
      } else {                      // v (B-frag layout: k-dim = key token)
        int vc = c - 192;
        val += bkv[96 + vc];
        int head = vc >> 5, d = vc & 31;
        int ktile = m >> 5, nt2 = d >> 4;
        sm2[(((head * 2 + ktile) * 2 + nt2) * 64 + (d & 15) + (((m & 31) >> 3) << 4)) * 8 + (m & 7)] = f2bf(val);
      }
    }
  }
  __syncthreads();

  // ---- phase 2: scores. unit u=(head,mtq); wave w owns u = 3w..3w+2
  f32x4 sc[3][4];
#pragma unroll
  for (int uu = 0; uu < 3; ++uu) {
    int u = w * 3 + uu, head = u >> 2, mtq = u & 3;
    bf16x8 aq = *(const bf16x8*)(sm1 + ((head * 4 + mtq) * 64 + lane) * 8);
#pragma unroll
    for (int nt = 0; nt < 4; ++nt) {
      bf16x8 bk = *(const bf16x8*)(sm1 + ((12 + head * 4 + nt) * 64 + lane) * 8);
      f32x4 z = {0.f, 0.f, 0.f, 0.f};
      sc[uu][nt] = MFMA(aq, bk, z);
    }
  }
  __syncthreads();   // all q/k reads done; sm1 may now be overwritten with P

  // ---- phase 3: +rpb bias, softmax (in-register), write P to A-swz LDS
#pragma unroll
  for (int uu = 0; uu < 3; ++uu) {
    int u = w * 3 + uu, head = u >> 2, mtq = u & 3;
#pragma unroll
    for (int nt = 0; nt < 4; ++nt) {
      int ktok = nt * 16 + lcol;
#pragma unroll
      for (int r = 0; r < 4; ++r) {
        int qtok = mtq * 16 + lrow * 4 + r;
        int dy = (qtok >> 3) - (ktok >> 3) + 7;
        int dx = (qtok & 7) - (ktok & 7) + 7;
        sc[uu][nt][r] += rpb[(dy * 15 + dx) * 3 + head];
      }
    }
#pragma unroll
    for (int r = 0; r < 4; ++r) {
      float mx = fmaxf(fmaxf(sc[uu][0][r], sc[uu][1][r]), fmaxf(sc[uu][2][r], sc[uu][3][r]));
#pragma unroll
      for (int off = 1; off <= 8; off <<= 1) mx = fmaxf(mx, __shfl_xor(mx, off, 64));
      float p[4], sum = 0.f;
#pragma unroll
      for (int nt = 0; nt < 4; ++nt) { p[nt] = __expf(sc[uu][nt][r] - mx); sum += p[nt]; }
#pragma unroll
      for (int off = 1; off <= 8; off <<= 1) sum += __shfl_xor(sum, off, 64);
      float inv = 1.f / sum;
#pragma unroll
      for (int nt = 0; nt < 4; ++nt) sc[uu][nt][r] = p[nt] * inv;
    }
#pragma unroll
    for (int nt = 0; nt < 4; ++nt) {
      int ktok = nt * 16 + lcol;
      int ktile = ktok >> 5, lhi = (ktok & 31) >> 3;
#pragma unroll
      for (int r = 0; r < 4; ++r) {
        int mm = lrow * 4 + r;
        sm1[(((head * 4 + mtq) * 2 + ktile) * 64 + mm + (lhi << 4)) * 8 + (ktok & 7)] = f2bf(sc[uu][nt][r]);
      }
    }
  }
  __syncthreads();

  // ---- phase 4: PV, write y to A-swz LDS (reuse sm0; head = k-tile)
#pragma unroll
  for (int uu = 0; uu < 3; ++uu) {
    int u = w * 3 + uu, head = u >> 2, mtq = u & 3;
#pragma unroll
    for (int nt2 = 0; nt2 < 2; ++nt2) {
      f32x4 acc = {0.f, 0.f, 0.f, 0.f};
#pragma unroll
      for (int ktile = 0; ktile < 2; ++ktile) {
        bf16x8 ap = *(const bf16x8*)(sm1 + (((head * 4 + mtq) * 2 + ktile) * 64 + lane) * 8);
        bf16x8 bv8 = *(const bf16x8*)(sm2 + (((head * 2 + ktile) * 2 + nt2) * 64 + lane) * 8);
        acc = MFMA(ap, bv8, acc);
      }
      int d0 = nt2 * 16 + lcol;
#pragma unroll
      for (int r = 0; r < 4; ++r) {
        int mm = lrow * 4 + r;
        sm0[((mtq * 3 + head) * 64 + mm + ((d0 >> 3) << 4)) * 8 + (d0 & 7)] = f2bf(acc[r]);
      }
    }
  }
  __syncthreads();

  // ---- phase 5: proj + bias + residual -> x2
  bf16x8 ay[3];
#pragma unroll
  for (int kt = 0; kt < 3; ++kt) ay[kt] = *(const bf16x8*)(sm0 + ((w * 3 + kt) * 64 + lane) * 8);
#pragma unroll
  for (int nt = 0; nt < 6; ++nt) {
    f32x4 acc = {0.f, 0.f, 0.f, 0.f};
#pragma unroll
    for (int kt = 0; kt < 3; ++kt) acc = MFMA(ay[kt], ldw(wswz, WP_T + kt * 6 + nt, lane), acc);
    int c = nt * 16 + lcol;
    float bpc = bp[c];
#pragma unroll
    for (int r = 0; r < 4; ++r) x2[rowoff[r] + c] = acc[r] + bpc + xv[r][nt];
  }
}

// ---------------- FUSED LeFF: LN2+FC1+GELU+dwconv+GELU+FC2+residual --------
// Channel-sixths (64 ch/phase). h: f32 [100 tokens][stride 68] = 26.6KB LDS
// (unioned with the phase-A xn A-frag buffer) -> 5 blocks/CU. Conv math is
// f32x4 FMA straight from LDS (no unpack); dw weights/bias stream from L1.
__global__ __launch_bounds__(256) void kleff(
    const float* __restrict__ x2, const float* __restrict__ g2,
    const float* __restrict__ b2, const float* __restrict__ bl1,
    const float* __restrict__ wdwT, const float* __restrict__ bdw,
    const float* __restrict__ bl2, const unsigned short* __restrict__ wswz,
    float* __restrict__ out) {
  __shared__ __align__(16) float smemf[100 * 68];          // 26.6KB
  unsigned short* smem16 = (unsigned short*)smemf;         // phase-A alias

  const int tid = threadIdx.x, lane = tid & 63, w = tid >> 6;
  const int lrow = lane >> 4, lcol = lane & 15;
  const int bid = xcd_swz(blockIdx.x);
  const int b = bid >> 10, ty0 = ((bid >> 5) & 31) * 8, tx0 = (bid & 31) * 8;

  const int mt1 = (w < 3) ? 4 + w : 3;   // 7 m-tiles; w=3 duplicates tile 3
  unsigned vmask = 0;                    // halo-token in-image bits (mi*4+r)

  // ---- phase A: LN2 over 10x10 halo tokens -> xn A-frag region of smem
  {
    float gv[6], bv[6];
#pragma unroll
    for (int nt = 0; nt < 6; ++nt) { gv[nt] = g2[nt * 16 + lcol]; bv[nt] = b2[nt * 16 + lcol]; }
#pragma unroll
    for (int mi = 0; mi < 2; ++mi) {
      const int mt = mi ? mt1 : w;
      float xv[4][6];
#pragma unroll
      for (int r = 0; r < 4; ++r) {
        int t = mt * 16 + lrow * 4 + r;
        int hy = (t * 205) >> 11, hx = t - hy * 10;     // t/10, t%10 for t<112
        int gy = ty0 - 1 + hy, gx = tx0 - 1 + hx;
        bool ok = ((unsigned)gy < 256u) && ((unsigned)gx < 256u) && (t < 100);
        vmask |= (ok ? 1u : 0u) << (mi * 4 + r);
        int cgy = min(max(gy, 0), 255), cgx = min(max(gx, 0), 255);
        long roff = ((long)b * 65536 + cgy * 256 + cgx) * 96;
#pragma unroll
        for (int nt = 0; nt < 6; ++nt) xv[r][nt] = x2[roff + nt * 16 + lcol];
      }
#pragma unroll
      for (int r = 0; r < 4; ++r) {
        float s = 0.f, sq = 0.f;
#pragma unroll
        for (int nt = 0; nt < 6; ++nt) { float v = xv[r][nt]; s += v; sq += v * v; }
#pragma unroll
        for (int off = 1; off <= 8; off <<= 1) { s += __shfl_xor(s, off, 64); sq += __shfl_xor(sq, off, 64); }
        float mean = s * (1.f / 96.f);
        float var = sq * (1.f / 96.f) - mean * mean;
        float rs = rsqrtf(var + 1e-5f);
        int mm = lrow * 4 + r;
#pragma unroll
        for (int nt = 0; nt < 6; ++nt) {
          float val = (xv[r][nt] - mean) * rs * gv[nt] + bv[nt];
          int c = nt * 16 + lcol;
          int kt = c >> 5;
          int lanew = mm + (((c & 31) >> 3) << 4);
          smem16[((mt * 3 + kt) * 64 + lanew) * 8 + (c & 7)] = f2bf(val);
        }
      }
    }
  }
  __syncthreads();

  // A-frags for FC1 (both owned m-tiles) -> registers, then smem is reusable
  bf16x8 af0[3], af1[3];
#pragma unroll
  for (int kt = 0; kt < 3; ++kt) {
    af0[kt] = *(const bf16x8*)(smem16 + ((w * 3 + kt) * 64 + lane) * 8);
    af1[kt] = *(const bf16x8*)(smem16 + ((mt1 * 3 + kt) * 64 + lane) * 8);
  }
  __syncthreads();

  f32x4 acc[6];
#pragma unroll
  for (int nt = 0; nt < 6; ++nt) { f32x4 z = {0.f, 0.f, 0.f, 0.f}; acc[nt] = z; }

  const int pint = w * 16 + lcol;         // lane's interior pixel 0..63
  const int iy = pint >> 3, ix = pint & 7;
  const int t0base = w * 16 + lrow * 4;
  const int t1base = mt1 * 16 + lrow * 4;

#pragma unroll
  for (int s = 0; s < 6; ++s) {
    // ---- FC1 sixth s: 4 n-tiles -> gelu(f32) -> h[token][c] (OOI zeroed)
#pragma unroll
    for (int ntl = 0; ntl < 4; ++ntl) {
      int nt = s * 4 + ntl;
      bf16x8 wf0 = ldw(wswz, W1_T + nt, lane);
      bf16x8 wf1 = ldw(wswz, W1_T + 24 + nt, lane);
      bf16x8 wf2 = ldw(wswz, W1_T + 48 + nt, lane);
      float bb = bl1[nt * 16 + lcol];
      f32x4 a0 = {0.f, 0.f, 0.f, 0.f}, a1 = {0.f, 0.f, 0.f, 0.f};
      a0 = MFMA(af0[0], wf0, a0); a0 = MFMA(af0[1], wf1, a0); a0 = MFMA(af0[2], wf2, a0);
      a1 = MFMA(af1[0], wf0, a1); a1 = MFMA(af1[1], wf1, a1); a1 = MFMA(af1[2], wf2, a1);
      const int c = ntl * 16 + lcol;      // local channel 0..63
#pragma unroll
      for (int r = 0; r < 4; ++r) {
        int t0 = t0base + r;
        if (t0 < 100)
          smemf[t0 * 68 + c] = ((vmask >> r) & 1u) ? gelu(a0[r] + bb) : 0.f;
        int t1 = t1base + r;
        if (t1 < 100)
          smemf[t1 * 68 + c] = ((vmask >> (4 + r)) & 1u) ? gelu(a1[r] + bb) : 0.f;
      }
    }
    __syncthreads();

    // ---- conv + FC2 sixth s: 2 k-tiles; data from LDS f32, weights from L1
#pragma unroll
    for (int ktl = 0; ktl < 2; ++ktl) {
      const int ktg = s * 2 + ktl;              // global k-tile 0..11
      const int chg = ktg * 32 + lrow * 8;      // global channel for weights
      const float* hp = smemf + (iy * 10 + ix) * 68 + ktl * 32 + lrow * 8;
      f32x4 alo = {0.f, 0.f, 0.f, 0.f}, ahi = {0.f, 0.f, 0.f, 0.f};
#pragma unroll
      for (int dy = 0; dy < 3; ++dy)
#pragma unroll
        for (int dx = 0; dx < 3; ++dx) {
          const float* hq = hp + (dy * 10 + dx) * 68;
          f32x4 dlo = *(const f32x4*)hq;
          f32x4 dhi = *(const f32x4*)(hq + 4);
          const float* wt = wdwT + (dy * 3 + dx) * 384 + chg;
          f32x4 wlo = *(const f32x4*)wt;
          f32x4 whi = *(const f32x4*)(wt + 4);
          alo += dlo * wlo;
          ahi += dhi * whi;
        }
      f32x4 blo = *(const f32x4*)(bdw + chg);
      f32x4 bhi = *(const f32x4*)(bdw + chg + 4);
      union { unsigned u[4]; bf16x8 v; } pk;
      pk.u[0] = cvtpk_bf16(gelu(alo.x + blo.x), gelu(alo.y + blo.y));
      pk.u[1] = cvtpk_bf16(gelu(alo.z + blo.z), gelu(alo.w + blo.w));
      pk.u[2] = cvtpk_bf16(gelu(ahi.x + bhi.x), gelu(ahi.y + bhi.y));
      pk.u[3] = cvtpk_bf16(gelu(ahi.z + bhi.z), gelu(ahi.w + bhi.w));
#pragma unroll
      for (int nt = 0; nt < 6; ++nt)
        acc[nt] = MFMA(pk.v, ldw(wswz, W2_T + ktg * 6 + nt, lane), acc[nt]);
    }
    __syncthreads();   // before next sixth overwrites h
  }

  // ---- epilogue: + bl2 + residual(x2) -> out (interior tokens)
#pragma unroll
  for (int nt = 0; nt < 6; ++nt) {
    int c = nt * 16 + lcol;
    float bb = bl2[c];
#pragma unroll
    for (int r = 0; r < 4; ++r) {
      int mm = w * 16 + lrow * 4 + r;
      int oy = ty0 + (mm >> 3), ox = tx0 + (mm & 7);
      long row = (long)b * 65536 + oy * 256 + ox;
      out[row * 96 + c] = acc[nt][r] + bb + x2[row * 96 + c];
    }
  }
}

// ---------------------------------------------------------------------------
extern "C" void kernel_launch(void* const* d_in, const int* in_sizes, int n_in,
                              void* d_out, int out_size, void* d_ws, size_t ws_size,
                              hipStream_t stream) {
  const float* x   = (const float*)d_in[0];
  const float* g1  = (const float*)d_in[1];
  const float* b1  = (const float*)d_in[2];
  const float* wq  = (const float*)d_in[3];
  const float* bq  = (const float*)d_in[4];
  const float* wkv = (const float*)d_in[5];
  const float* bkv = (const float*)d_in[6];
  const float* rpb = (const float*)d_in[7];
  const float* wp  = (const float*)d_in[8];
  const float* bp  = (const float*)d_in[9];
  const float* g2  = (const float*)d_in[10];
  const float* b2  = (const float*)d_in[11];
  const float* w1  = (const float*)d_in[12];
  const float* bl1 = (const float*)d_in[13];
  const float* wdw = (const float*)d_in[14];
  const float* bdw = (const float*)d_in[15];
  const float* w2  = (const float*)d_in[16];
  const float* bl2 = (const float*)d_in[17];

  char* ws = (char*)d_ws;
  unsigned short* wswz = (unsigned short*)ws;                      // 221 KB
  float* wdwT = (float*)(ws + (size_t)(256 << 10));                // 13.8 KB @256KB
  float* x2 = (float*)(ws + (size_t)(4 << 20));                    // 100.7 MB
  float* outp = (float*)d_out;

  kwconv<<<68, 256, 0, stream>>>(wq, wkv, wp, w1, w2, wdw, wswz, wdwT);
  kattn<<<4096, 256, 0, stream>>>(x, g1, b1, bq, bkv, rpb, bp, wswz, x2);
  kleff<<<4096, 256, 0, stream>>>(x2, g2, b2, bl1, wdwT, bdw, bl2, wswz, outp);
}

// Round 11
// 700.812 us; speedup vs baseline: 1.0108x; 1.0108x over previous
//
#include <hip/hip_runtime.h>
#include <math.h>

// ---------------------------------------------------------------------------
// Swin/Uformer block, MI355X. Sizes fixed: B=4 H=W=256 C=96 NH=3 HD=32 WIN=8
// N=64 HID=384. 3 kernels:
//   kwconv : f32 weights -> bf16 pre-swizzled B-frags; + wdw transposed f32
//   kattn  : LN1 + QKV + window-attn (+rpb bias, softmax) + proj + residual
//   kleff  : FUSED LN2+FC1+GELU+dwconv3x3+GELU+FC2+residual, channel-QUARTERS
//            with DOUBLE-BUFFERED h (2 x 19.4KB bf16): phase k overlaps
//            FC1(q+1) (MFMA+global) with conv+FC2(q) (LDS+VALU).
// MFMA 16x16x32 bf16 layouts used throughout:
//   A-frag: lane = (m%16) + 16*(k%32/8), elem = k%8
//   B-frag: lane = (n%16) + 16*(k%32/8), elem = k%8
//   C/D   : row  = 4*(lane/16)+reg, col = lane%16
// ---------------------------------------------------------------------------

typedef __attribute__((ext_vector_type(8))) short bf16x8;
typedef __attribute__((ext_vector_type(4))) float f32x4;
typedef __attribute__((ext_vector_type(2))) float f32x2;

#define MFMA(a, b, c) __builtin_amdgcn_mfma_f32_16x16x32_bf16((a), (b), (c), 0, 0, 0)

// weight tile bases (in 16x32 B-fragment tiles of 64 lanes * 16B)
#define WQ_T 0
#define WKV_T 18
#define WP_T 54
#define W1_T 72
#define W2_T 144
#define NTILES_TOT 216

__device__ __forceinline__ unsigned short f2bf(float f) {
  union { float f; unsigned u; } v; v.f = f;
  unsigned r = v.u + 0x7FFFu + ((v.u >> 16) & 1u);
  return (unsigned short)(r >> 16);
}
__device__ __forceinline__ float asf(unsigned u) {
  union { unsigned u; float f; } v; v.u = u; return v.f;
}
__device__ __forceinline__ unsigned cvtpk_bf16(float lo, float hi) {
  unsigned r;
  asm("v_cvt_pk_bf16_f32 %0, %1, %2" : "=v"(r) : "v"(lo), "v"(hi));
  return r;
}
// gelu(x) = x * sigmoid(2z), z = 0.7978845608 x (1 + 0.044715 x^2)
__device__ __forceinline__ float gelu(float x) {
  float t = x * x;
  float w = x * fmaf(t, -0.07135941f, -1.5957691f);   // -2z
  float a = __expf(w);
  return x * __builtin_amdgcn_rcpf(1.f + a);
}
__device__ __forceinline__ bf16x8 ldw(const unsigned short* wswz, int tile, int lane) {
  return *(const bf16x8*)(wswz + ((size_t)(tile * 64 + lane)) * 8);
}
__device__ __forceinline__ int xcd_swz(int bid) {   // 4096 % 8 == 0 -> bijective
  return (bid & 7) * 512 + (bid >> 3);
}

// --------------------------- weight convert/swizzle ------------------------
__global__ void kwconv(const float* __restrict__ wq, const float* __restrict__ wkv,
                       const float* __restrict__ wp, const float* __restrict__ w1,
                       const float* __restrict__ w2, const float* __restrict__ wdw,
                       unsigned short* __restrict__ wswz, float* __restrict__ wdwT) {
  int tid = blockIdx.x * 256 + threadIdx.x;
  if (tid >= NTILES_TOT * 64) {
    int i = tid - NTILES_TOT * 64;
    if (i < 3456) {                       // wdw (384,1,3,3) -> wdwT [tap][384]
      int ch = i % 384, tap = i / 384;
      wdwT[tap * 384 + ch] = wdw[ch * 9 + tap];
    }
    return;
  }
  int e = tid; const float* src; int N, NT;
  if (e < 1152)      { src = wq;  N = 96;  NT = 6; }
  else if (e < 3456) { src = wkv; N = 192; NT = 12; e -= 1152; }
  else if (e < 4608) { src = wp;  N = 96;  NT = 6;  e -= 3456; }
  else if (e < 9216) { src = w1;  N = 384; NT = 24; e -= 4608; }
  else               { src = w2;  N = 96;  NT = 6;  e -= 9216; }
  int lane = e & 63, t = e >> 6;
  int nt = t % NT, kt = t / NT;
  int k0 = kt * 32 + (lane >> 4) * 8;
  int n = nt * 16 + (lane & 15);
  unsigned short* dst = wswz + (size_t)tid * 8;
#pragma unroll
  for (int i = 0; i < 8; ++i) dst[i] = f2bf(src[(size_t)(k0 + i) * N + n]);
}

// --------------------------- attention block -------------------------------
__global__ __launch_bounds__(256) void kattn(
    const float* __restrict__ x, const float* __restrict__ g1, const float* __restrict__ b1,
    const float* __restrict__ bq, const float* __restrict__ bkv,
    const float* __restrict__ rpb, const float* __restrict__ bp,
    const unsigned short* __restrict__ wswz, float* __restrict__ x2) {
  __shared__ __align__(16) unsigned short sm0[4 * 3 * 64 * 8];   // xn_swz, later y_swz (12KB)
  __shared__ __align__(16) unsigned short sm1[24 * 64 * 8];      // q(12 tiles)+k(12) then p(24) (24KB)
  __shared__ __align__(16) unsigned short sm2[3 * 2 * 2 * 64 * 8]; // v (12KB)

  const int tid = threadIdx.x;
  const int lane = tid & 63, w = tid >> 6;
  const int lrow = lane >> 4, lcol = lane & 15;
  const int wi = xcd_swz(blockIdx.x);
  const int b = wi >> 10, wy = (wi >> 5) & 31, wx = wi & 31;

  long rowoff[4];
#pragma unroll
  for (int r = 0; r < 4; ++r) {
    int m = w * 16 + lrow * 4 + r;
    int gy = wy * 8 + (m >> 3), gx = wx * 8 + (m & 7);
    rowoff[r] = ((long)b * 65536 + gy * 256 + gx) * 96;
  }

  // ---- phase 0: load x (C/D-layout regs), LN1, write xn to A-swz LDS
  float xv[4][6], xn[4][6], gv[6], bv[6];
#pragma unroll
  for (int nt = 0; nt < 6; ++nt) {
    int c = nt * 16 + lcol;
    gv[nt] = g1[c]; bv[nt] = b1[c];
#pragma unroll
    for (int r = 0; r < 4; ++r) xv[r][nt] = x[rowoff[r] + c];
  }
#pragma unroll
  for (int r = 0; r < 4; ++r) {
    float s = 0.f, sq = 0.f;
#pragma unroll
    for (int nt = 0; nt < 6; ++nt) { float v = xv[r][nt]; s += v; sq += v * v; }
#pragma unroll
    for (int off = 1; off <= 8; off <<= 1) { s += __shfl_xor(s, off, 64); sq += __shfl_xor(sq, off, 64); }
    float mean = s * (1.f / 96.f);
    float var = sq * (1.f / 96.f) - mean * mean;
    float rs = rsqrtf(var + 1e-5f);
#pragma unroll
    for (int nt = 0; nt < 6; ++nt) xn[r][nt] = (xv[r][nt] - mean) * rs * gv[nt] + bv[nt];
  }
#pragma unroll
  for (int r = 0; r < 4; ++r) {
    int mm = lrow * 4 + r;
#pragma unroll
    for (int nt = 0; nt < 6; ++nt) {
      int c = nt * 16 + lcol;
      int kt = c >> 5;
      int lanew = mm + (((c & 31) >> 3) << 4);
      sm0[((w * 3 + kt) * 64 + lanew) * 8 + (c & 7)] = f2bf(xn[r][nt]);
    }
  }
  __syncthreads();

  // ---- phase 1: QKV GEMM (M=64 N=288 K=96), wave w owns m-tile w
  bf16x8 af[3];
#pragma unroll
  for (int kt = 0; kt < 3; ++kt) af[kt] = *(const bf16x8*)(sm0 + ((w * 3 + kt) * 64 + lane) * 8);
  for (int nt = 0; nt < 18; ++nt) {
    f32x4 acc = {0.f, 0.f, 0.f, 0.f};
#pragma unroll
    for (int kt = 0; kt < 3; ++kt) {
      int tile = (nt < 6) ? (WQ_T + kt * 6 + nt) : (WKV_T + kt * 12 + (nt - 6));
      acc = MFMA(af[kt], ldw(wswz, tile, lane), acc);
    }
    int c = nt * 16 + lcol;
#pragma unroll
    for (int r = 0; r < 4; ++r) {
      int m = w * 16 + lrow * 4 + r;
      float val = acc[r];
      if (c < 96) {                 // q (pre-scaled)
        val = (val + bq[c]) * 0.17677669529663687f;
        int head = c >> 5, d = c & 31;
        sm1[((head * 4 + w) * 64 + (m & 15) + ((d >> 3) << 4)) * 8 + (d & 7)] = f2bf(val);
      } else if (c < 192) {         // k
        int kc = c - 96;
        val += bkv[kc];
        int head = kc >> 5, d = kc & 31;
        sm1[((12 + head * 4 + w) * 64 + (m & 15) + ((d >> 3) << 4)) * 8 + (d & 7)] = f2bf(val);
      } else {                      // v (B-frag layout: k-dim = key token)
        int vc = c - 192;
        val += bkv[96 + vc];
        int head = vc >> 5, d = vc & 31;
        int ktile = m >> 5, nt2 = d >> 4;
        sm2[(((head * 2 + ktile) * 2 + nt2) * 64 + (d & 15) + (((m & 31) >> 3) << 4)) * 8 + (m & 7)] = f2bf(val);
      }
    }
  }
  __syncthreads();

  // ---- phase 2: scores. unit u=(head,mtq); wave w owns u = 3w..3w+2
  f32x4 sc[3][4];
#pragma unroll
  for (int uu = 0; uu < 3; ++uu) {
    int u = w * 3 + uu, head = u >> 2, mtq = u & 3;
    bf16x8 aq = *(const bf16x8*)(sm1 + ((head * 4 + mtq) * 64 + lane) * 8);
#pragma unroll
    for (int nt = 0; nt < 4; ++nt) {
      bf16x8 bk = *(const bf16x8*)(sm1 + ((12 + head * 4 + nt) * 64 + lane) * 8);
      f32x4 z = {0.f, 0.f, 0.f, 0.f};
      sc[uu][nt] = MFMA(aq, bk, z);
    }
  }
  __syncthreads();   // all q/k reads done; sm1 may now be overwritten with P

  // ---- phase 3: +rpb bias, softmax (in-register), write P to A-swz LDS
#pragma unroll
  for (int uu = 0; uu < 3; ++uu) {
    int u = w * 3 + uu, head = u >> 2, mtq = u & 3;
#pragma unroll
    for (int nt = 0; nt < 4; ++nt) {
      int ktok = nt * 16 + lcol;
#pragma unroll
      for (int r = 0; r < 4; ++r) {
        int qtok = mtq * 16 + lrow * 4 + r;
        int dy = (qtok >> 3) - (ktok >> 3) + 7;
        int dx = (qtok & 7) - (ktok & 7) + 7;
        sc[uu][nt][r] += rpb[(dy * 15 + dx) * 3 + head];
      }
    }
#pragma unroll
    for (int r = 0; r < 4; ++r) {
      float mx = fmaxf(fmaxf(sc[uu][0][r], sc[uu][1][r]), fmaxf(sc[uu][2][r], sc[uu][3][r]));
#pragma unroll
      for (int off = 1; off <= 8; off <<= 1) mx = fmaxf(mx, __shfl_xor(mx, off, 64));
      float p[4], sum = 0.f;
#pragma unroll
      for (int nt = 0; nt < 4; ++nt) { p[nt] = __expf(sc[uu][nt][r] - mx); sum += p[nt]; }
#pragma unroll
      for (int off = 1; off <= 8; off <<= 1) sum += __shfl_xor(sum, off, 64);
      float inv = 1.f / sum;
#pragma unroll
      for (int nt = 0; nt < 4; ++nt) sc[uu][nt][r] = p[nt] * inv;
    }
#pragma unroll
    for (int nt = 0; nt < 4; ++nt) {
      int ktok = nt * 16 + lcol;
      int ktile = ktok >> 5, lhi = (ktok & 31) >> 3;
#pragma unroll
      for (int r = 0; r < 4; ++r) {
        int mm = lrow * 4 + r;
        sm1[(((head * 4 + mtq) * 2 + ktile) * 64 + mm + (lhi << 4)) * 8 + (ktok & 7)] = f2bf(sc[uu][nt][r]);
      }
    }
  }
  __syncthreads();

  // ---- phase 4: PV, write y to A-swz LDS (reuse sm0; head = k-tile)
#pragma unroll
  for (int uu = 0; uu < 3; ++uu) {
    int u = w * 3 + uu, head = u >> 2, mtq = u & 3;
#pragma unroll
    for (int nt2 = 0; nt2 < 2; ++nt2) {
      f32x4 acc = {0.f, 0.f, 0.f, 0.f};
#pragma unroll
      for (int ktile = 0; ktile < 2; ++ktile) {
        bf16x8 ap = *(const bf16x8*)(sm1 + (((head * 4 + mtq) * 2 + ktile) * 64 + lane) * 8);
        bf16x8 bv8 = *(const bf16x8*)(sm2 + (((head * 2 + ktile) * 2 + nt2) * 64 + lane) * 8);
        acc = MFMA(ap, bv8, acc);
      }
      int d0 = nt2 * 16 + lcol;
#pragma unroll
      for (int r = 0; r < 4; ++r) {
        int mm = lrow * 4 + r;
        sm0[((mtq * 3 + head) * 64 + mm + ((d0 >> 3) << 4)) * 8 + (d0 & 7)] = f2bf(acc[r]);
      }
    }
  }
  __syncthreads();

  // ---- phase 5: proj + bias + residual -> x2
  bf16x8 ay[3];
#pragma unroll
  for (int kt = 0; kt < 3; ++kt) ay[kt] = *(const bf16x8*)(sm0 + ((w * 3 + kt) * 64 + lane) * 8);
#pragma unroll
  for (int nt = 0; nt < 6; ++nt) {
    f32x4 acc = {0.f, 0.f, 0.f, 0.f};
#pragma unroll
    for (int kt = 0; kt < 3; ++kt) acc = MFMA(ay[kt], ldw(wswz, WP_T + kt * 6 + nt, lane), acc);
    int c = nt * 16 + lcol;
    float bpc = bp[c];
#pragma unroll
    for (int r = 0; r < 4; ++r) x2[rowoff[r] + c] = acc[r] + bpc + xv[r][nt];
  }
}

// ---------------- FUSED LeFF: LN2+FC1+GELU+dwconv+GELU+FC2+residual --------
// Channel-quarters (96 ch), double-buffered h (bf16 [12g][101t][8e], 19.4KB
// each). Phase k overlaps FC1(q+1)->buf[(q+1)&1] with conv+FC2(q)<-buf[q&1].
__device__ __forceinline__ bf16x8 dwconv_gelu_g(
    const unsigned short* h00,                    // LDS ptr at tap (0,0)
    const float* __restrict__ wdwT, const float* __restrict__ bdw, int ch) {
  f32x2 a2[4];
#pragma unroll
  for (int j = 0; j < 4; ++j) a2[j] = (f32x2){0.f, 0.f};
#pragma unroll
  for (int dy = 0; dy < 3; ++dy) {
    uint4 dv[3];
#pragma unroll
    for (int dx = 0; dx < 3; ++dx)
      dv[dx] = *(const uint4*)(h00 + (dy * 10 + dx) * 8);
#pragma unroll
    for (int dx = 0; dx < 3; ++dx) {
      int t = dy * 3 + dx;
      f32x4 wlo = *(const f32x4*)(wdwT + t * 384 + ch);
      f32x4 whi = *(const f32x4*)(wdwT + t * 384 + ch + 4);
      const unsigned* du = (const unsigned*)&dv[dx];
      f32x2 d0 = { asf(du[0] << 16), asf(du[0] & 0xffff0000u) };
      f32x2 d1 = { asf(du[1] << 16), asf(du[1] & 0xffff0000u) };
      f32x2 d2 = { asf(du[2] << 16), asf(du[2] & 0xffff0000u) };
      f32x2 d3 = { asf(du[3] << 16), asf(du[3] & 0xffff0000u) };
      f32x2 w0 = {wlo.x, wlo.y}, w1 = {wlo.z, wlo.w};
      f32x2 w2v = {whi.x, whi.y}, w3 = {whi.z, whi.w};
      a2[0] += d0 * w0; a2[1] += d1 * w1; a2[2] += d2 * w2v; a2[3] += d3 * w3;
    }
  }
  f32x4 blo = *(const f32x4*)(bdw + ch);
  f32x4 bhi = *(const f32x4*)(bdw + ch + 4);
  union { unsigned u[4]; bf16x8 v; } pk;
  pk.u[0] = cvtpk_bf16(gelu(a2[0].x + blo.x), gelu(a2[0].y + blo.y));
  pk.u[1] = cvtpk_bf16(gelu(a2[1].x + blo.z), gelu(a2[1].y + blo.w));
  pk.u[2] = cvtpk_bf16(gelu(a2[2].x + bhi.x), gelu(a2[2].y + bhi.y));
  pk.u[3] = cvtpk_bf16(gelu(a2[3].x + bhi.z), gelu(a2[3].y + bhi.w));
  return pk.v;
}

// FC1 quarter q (6 n-tiles, 96 ch) -> dst h buffer [12g][101t][8e]
#define FC1Q(q, dst)                                                          \
  {                                                                           \
    _Pragma("unroll")                                                         \
    for (int ntl = 0; ntl < 6; ++ntl) {                                       \
      int nt = (q) * 6 + ntl;                                                 \
      bf16x8 wf0 = ldw(wswz, W1_T + nt, lane);                                \
      bf16x8 wf1 = ldw(wswz, W1_T + 24 + nt, lane);                           \
      bf16x8 wf2 = ldw(wswz, W1_T + 48 + nt, lane);                           \
      float bb = bl1[(q) * 96 + ntl * 16 + lcol];                             \
      f32x4 a0 = {0.f, 0.f, 0.f, 0.f}, a1 = {0.f, 0.f, 0.f, 0.f};             \
      a0 = MFMA(af0[0], wf0, a0); a0 = MFMA(af0[1], wf1, a0);                 \
      a0 = MFMA(af0[2], wf2, a0);                                             \
      a1 = MFMA(af1[0], wf0, a1); a1 = MFMA(af1[1], wf1, a1);                 \
      a1 = MFMA(af1[2], wf2, a1);                                             \
      const int g = ntl * 2 + (lcol >> 3);                                    \
      const int e = lcol & 7;                                                 \
      _Pragma("unroll")                                                       \
      for (int r = 0; r < 4; ++r) {                                           \
        int t0 = t0base + r;                                                  \
        if (t0 < 100)                                                         \
          (dst)[g * 808 + t0 * 8 + e] =                                       \
              ((vmask >> r) & 1u) ? f2bf(gelu(a0[r] + bb)) : (unsigned short)0; \
        int t1 = t1base + r;                                                  \
        if (t1 < 100)                                                         \
          (dst)[g * 808 + t1 * 8 + e] =                                       \
              ((vmask >> (4 + r)) & 1u) ? f2bf(gelu(a1[r] + bb)) : (unsigned short)0; \
      }                                                                       \
    }                                                                         \
  }

// conv + FC2 quarter q (3 k-tiles) <- src h buffer
#define CONVQ(q, src)                                                         \
  {                                                                           \
    _Pragma("unroll")                                                         \
    for (int ktl = 0; ktl < 3; ++ktl) {                                       \
      const int ktg = (q) * 3 + ktl;                                          \
      const unsigned short* h00 =                                             \
          (src) + (ktl * 4 + lrow) * 808 + (iy * 10 + ix) * 8;                \
      bf16x8 pk = dwconv_gelu_g(h00, wdwT, bdw, ktg * 32 + lrow * 8);         \
      _Pragma("unroll")                                                       \
      for (int nt = 0; nt < 6; ++nt)                                          \
        acc[nt] = MFMA(pk, ldw(wswz, W2_T + ktg * 6 + nt, lane), acc[nt]);    \
    }                                                                         \
  }

__global__ __launch_bounds__(256) void kleff(
    const float* __restrict__ x2, const float* __restrict__ g2,
    const float* __restrict__ b2, const float* __restrict__ bl1,
    const float* __restrict__ wdwT, const float* __restrict__ bdw,
    const float* __restrict__ bl2, const unsigned short* __restrict__ wswz,
    float* __restrict__ out) {
  // 2 h buffers (bf16 [12][101][8] = 9696 elems each); phase-A xn aliases both
  __shared__ __align__(16) unsigned short smem[2 * 9696];    // 38.8KB

  const int tid = threadIdx.x, lane = tid & 63, w = tid >> 6;
  const int lrow = lane >> 4, lcol = lane & 15;
  const int bid = xcd_swz(blockIdx.x);
  const int b = bid >> 10, ty0 = ((bid >> 5) & 31) * 8, tx0 = (bid & 31) * 8;

  const int mt1 = (w < 3) ? 4 + w : 3;   // 7 m-tiles; w=3 duplicates tile 3
  unsigned vmask = 0;                    // halo-token in-image bits (mi*4+r)

  // ---- phase A: LN2 over 10x10 halo tokens -> xn A-frag region of smem
  {
    float gv[6], bv[6];
#pragma unroll
    for (int nt = 0; nt < 6; ++nt) { gv[nt] = g2[nt * 16 + lcol]; bv[nt] = b2[nt * 16 + lcol]; }
#pragma unroll
    for (int mi = 0; mi < 2; ++mi) {
      const int mt = mi ? mt1 : w;
      float xv[4][6];
#pragma unroll
      for (int r = 0; r < 4; ++r) {
        int t = mt * 16 + lrow * 4 + r;
        int hy = (t * 205) >> 11, hx = t - hy * 10;     // t/10, t%10 for t<112
        int gy = ty0 - 1 + hy, gx = tx0 - 1 + hx;
        bool ok = ((unsigned)gy < 256u) && ((unsigned)gx < 256u) && (t < 100);
        vmask |= (ok ? 1u : 0u) << (mi * 4 + r);
        int cgy = min(max(gy, 0), 255), cgx = min(max(gx, 0), 255);
        long roff = ((long)b * 65536 + cgy * 256 + cgx) * 96;
#pragma unroll
        for (int nt = 0; nt < 6; ++nt) xv[r][nt] = x2[roff + nt * 16 + lcol];
      }
#pragma unroll
      for (int r = 0; r < 4; ++r) {
        float s = 0.f, sq = 0.f;
#pragma unroll
        for (int nt = 0; nt < 6; ++nt) { float v = xv[r][nt]; s += v; sq += v * v; }
#pragma unroll
        for (int off = 1; off <= 8; off <<= 1) { s += __shfl_xor(s, off, 64); sq += __shfl_xor(sq, off, 64); }
        float mean = s * (1.f / 96.f);
        float var = sq * (1.f / 96.f) - mean * mean;
        float rs = rsqrtf(var + 1e-5f);
        int mm = lrow * 4 + r;
#pragma unroll
        for (int nt = 0; nt < 6; ++nt) {
          float val = (xv[r][nt] - mean) * rs * gv[nt] + bv[nt];
          int c = nt * 16 + lcol;
          int kt = c >> 5;
          int lanew = mm + (((c & 31) >> 3) << 4);
          smem[((mt * 3 + kt) * 64 + lanew) * 8 + (c & 7)] = f2bf(val);
        }
      }
    }
  }
  __syncthreads();

  // A-frags for FC1 (both owned m-tiles) -> registers, then smem is reusable
  bf16x8 af0[3], af1[3];
#pragma unroll
  for (int kt = 0; kt < 3; ++kt) {
    af0[kt] = *(const bf16x8*)(smem + ((w * 3 + kt) * 64 + lane) * 8);
    af1[kt] = *(const bf16x8*)(smem + ((mt1 * 3 + kt) * 64 + lane) * 8);
  }
  __syncthreads();

  f32x4 acc[6];
#pragma unroll
  for (int nt = 0; nt < 6; ++nt) { f32x4 z = {0.f, 0.f, 0.f, 0.f}; acc[nt] = z; }

  const int pint = w * 16 + lcol;         // lane's interior pixel 0..63
  const int iy = pint >> 3, ix = pint & 7;
  const int t0base = w * 16 + lrow * 4;
  const int t1base = mt1 * 16 + lrow * 4;

  unsigned short* bufA = smem;
  unsigned short* bufB = smem + 9696;

  // ---- software-pipelined quarters: FC1(q+1) overlaps conv+FC2(q)
  FC1Q(0, bufA);
  __syncthreads();
  FC1Q(1, bufB);  CONVQ(0, bufA);
  __syncthreads();
  FC1Q(2, bufA);  CONVQ(1, bufB);
  __syncthreads();
  FC1Q(3, bufB);  CONVQ(2, bufA);
  __syncthreads();
  CONVQ(3, bufB);

  // ---- epilogue: + bl2 + residual(x2) -> out (interior tokens)
#pragma unroll
  for (int nt = 0; nt < 6; ++nt) {
    int c = nt * 16 + lcol;
    float bb = bl2[c];
#pragma unroll
    for (int r = 0; r < 4; ++r) {
      int mm = w * 16 + lrow * 4 + r;
      int oy = ty0 + (mm >> 3), ox = tx0 + (mm & 7);
      long row = (long)b * 65536 + oy * 256 + ox;
      out[row * 96 + c] = acc[nt][r] + bb + x2[row * 96 + c];
    }
  }
}

// ---------------------------------------------------------------------------
extern "C" void kernel_launch(void* const* d_in, const int* in_sizes, int n_in,
                              void* d_out, int out_size, void* d_ws, size_t ws_size,
                              hipStream_t stream) {
  const float* x   = (const float*)d_in[0];
  const float* g1  = (const float*)d_in[1];
  const float* b1  = (const float*)d_in[2];
  const float* wq  = (const float*)d_in[3];
  const float* bq  = (const float*)d_in[4];
  const float* wkv = (const float*)d_in[5];
  const float* bkv = (const float*)d_in[6];
  const float* rpb = (const float*)d_in[7];
  const float* wp  = (const float*)d_in[8];
  const float* bp  = (const float*)d_in[9];
  const float* g2  = (const float*)d_in[10];
  const float* b2  = (const float*)d_in[11];
  const float* w1  = (const float*)d_in[12];
  const float* bl1 = (const float*)d_in[13];
  const float* wdw = (const float*)d_in[14];
  const float* bdw = (const float*)d_in[15];
  const float* w2  = (const float*)d_in[16];
  const float* bl2 = (const float*)d_in[17];

  char* ws = (char*)d_ws;
  unsigned short* wswz = (unsigned short*)ws;                      // 221 KB
  float* wdwT = (float*)(ws + (size_t)(256 << 10));                // 13.8 KB @256KB
  float* x2 = (float*)(ws + (size_t)(4 << 20));                    // 100.7 MB
  float* outp = (float*)d_out;

  kwconv<<<68, 256, 0, stream>>>(wq, wkv, wp, w1, w2, wdw, wswz, wdwT);
  kattn<<<4096, 256, 0, stream>>>(x, g1, b1, bq, bkv, rpb, bp, wswz, x2);
  kleff<<<4096, 256, 0, stream>>>(x2, g2, b2, bl1, wdwT, bdw, bl2, wswz, outp);
}

// Round 12
// 458.596 us; speedup vs baseline: 1.5447x; 1.5282x over previous
//
#include <hip/hip_runtime.h>
#include <math.h>

// ---------------------------------------------------------------------------
// Swin/Uformer block, MI355X. Sizes fixed: B=4 H=W=256 C=96 NH=3 HD=32 WIN=8
// N=64 HID=384. 3 kernels:
//   kwconv : f32 weights -> bf16 pre-swizzled B-frags; + wdw transposed f32
//   kattn  : LN1 + QKV + window-attn + proj + residual. QKV epilogue uses
//            SWAPPED MFMA (D=[channel][token]) for q/k -> b64 LDS stores,
//            normal orientation for v (consecutive tokens) -> b64 stores.
//   kleff  : FUSED LN2+FC1+GELU+dwconv3x3+GELU+FC2+residual, halves; FC1 uses
//            swapped MFMA so each lane packs 4 consecutive channels ->
//            ds_write_b64 into h[100][200]; conv reads contiguous b128.
// MFMA 16x16x32 bf16 layouts used throughout:
//   A-frag: lane = (row%16) + 16*(k%32/8), elem = k%8   (rows = left operand)
//   B-frag: lane = (col%16) + 16*(k%32/8), elem = k%8
//   C/D   : row  = 4*(lane/16)+reg, col = lane%16
// Swapped trick: MFMA(Wfrag, Xfrag) gives D[channel][token]; W B-frags and
// X A-frags have identical index math under row<->col swap, so no new data.
// ---------------------------------------------------------------------------

typedef __attribute__((ext_vector_type(8))) short bf16x8;
typedef __attribute__((ext_vector_type(4))) float f32x4;
typedef __attribute__((ext_vector_type(2))) float f32x2;

#define MFMA(a, b, c) __builtin_amdgcn_mfma_f32_16x16x32_bf16((a), (b), (c), 0, 0, 0)

#define WQ_T 0
#define WKV_T 18
#define WP_T 54
#define W1_T 72
#define W2_T 144
#define NTILES_TOT 216

__device__ __forceinline__ unsigned short f2bf(float f) {
  union { float f; unsigned u; } v; v.f = f;
  unsigned r = v.u + 0x7FFFu + ((v.u >> 16) & 1u);
  return (unsigned short)(r >> 16);
}
__device__ __forceinline__ float asf(unsigned u) {
  union { unsigned u; float f; } v; v.u = u; return v.f;
}
__device__ __forceinline__ unsigned cvtpk_bf16(float lo, float hi) {
  unsigned r;
  asm("v_cvt_pk_bf16_f32 %0, %1, %2" : "=v"(r) : "v"(lo), "v"(hi));
  return r;
}
// gelu(x) = x * sigmoid(2z), z = 0.7978845608 x (1 + 0.044715 x^2)
__device__ __forceinline__ float gelu(float x) {
  float t = x * x;
  float w = x * fmaf(t, -0.07135941f, -1.5957691f);   // -2z
  float a = __expf(w);
  return x * __builtin_amdgcn_rcpf(1.f + a);
}
__device__ __forceinline__ bf16x8 ldw(const unsigned short* wswz, int tile, int lane) {
  return *(const bf16x8*)(wswz + ((size_t)(tile * 64 + lane)) * 8);
}
__device__ __forceinline__ int xcd_swz(int bid) {   // 4096 % 8 == 0 -> bijective
  return (bid & 7) * 512 + (bid >> 3);
}

// --------------------------- weight convert/swizzle ------------------------
__global__ void kwconv(const float* __restrict__ wq, const float* __restrict__ wkv,
                       const float* __restrict__ wp, const float* __restrict__ w1,
                       const float* __restrict__ w2, const float* __restrict__ wdw,
                       unsigned short* __restrict__ wswz, float* __restrict__ wdwT) {
  int tid = blockIdx.x * 256 + threadIdx.x;
  if (tid >= NTILES_TOT * 64) {
    int i = tid - NTILES_TOT * 64;
    if (i < 3456) {                       // wdw (384,1,3,3) -> wdwT [tap][384]
      int ch = i % 384, tap = i / 384;
      wdwT[tap * 384 + ch] = wdw[ch * 9 + tap];
    }
    return;
  }
  int e = tid; const float* src; int N, NT;
  if (e < 1152)      { src = wq;  N = 96;  NT = 6; }
  else if (e < 3456) { src = wkv; N = 192; NT = 12; e -= 1152; }
  else if (e < 4608) { src = wp;  N = 96;  NT = 6;  e -= 3456; }
  else if (e < 9216) { src = w1;  N = 384; NT = 24; e -= 4608; }
  else               { src = w2;  N = 96;  NT = 6;  e -= 9216; }
  int lane = e & 63, t = e >> 6;
  int nt = t % NT, kt = t / NT;
  int k0 = kt * 32 + (lane >> 4) * 8;
  int n = nt * 16 + (lane & 15);
  unsigned short* dst = wswz + (size_t)tid * 8;
#pragma unroll
  for (int i = 0; i < 8; ++i) dst[i] = f2bf(src[(size_t)(k0 + i) * N + n]);
}

// --------------------------- attention block -------------------------------
__global__ __launch_bounds__(256) void kattn(
    const float* __restrict__ x, const float* __restrict__ g1, const float* __restrict__ b1,
    const float* __restrict__ bq, const float* __restrict__ bkv,
    const float* __restrict__ rpb, const float* __restrict__ bp,
    const unsigned short* __restrict__ wswz, float* __restrict__ x2) {
  __shared__ __align__(16) unsigned short sm0[4 * 3 * 64 * 8];   // xn_swz, later y_swz (12KB)
  __shared__ __align__(16) unsigned short sm1[24 * 64 * 8];      // q(12)+k(12) then p(24) (24KB)
  __shared__ __align__(16) unsigned short sm2[3 * 2 * 2 * 64 * 8]; // v (12KB)

  const int tid = threadIdx.x;
  const int lane = tid & 63, w = tid >> 6;
  const int lrow = lane >> 4, lcol = lane & 15;
  const int wi = xcd_swz(blockIdx.x);
  const int b = wi >> 10, wy = (wi >> 5) & 31, wx = wi & 31;

  long rowoff[4];
#pragma unroll
  for (int r = 0; r < 4; ++r) {
    int m = w * 16 + lrow * 4 + r;
    int gy = wy * 8 + (m >> 3), gx = wx * 8 + (m & 7);
    rowoff[r] = ((long)b * 65536 + gy * 256 + gx) * 96;
  }

  // ---- phase 0: load x (C/D-layout regs), LN1, write xn to A-swz LDS
  float xv[4][6], xn[4][6], gv[6], bv[6];
#pragma unroll
  for (int nt = 0; nt < 6; ++nt) {
    int c = nt * 16 + lcol;
    gv[nt] = g1[c]; bv[nt] = b1[c];
#pragma unroll
    for (int r = 0; r < 4; ++r) xv[r][nt] = x[rowoff[r] + c];
  }
#pragma unroll
  for (int r = 0; r < 4; ++r) {
    float s = 0.f, sq = 0.f;
#pragma unroll
    for (int nt = 0; nt < 6; ++nt) { float v = xv[r][nt]; s += v; sq += v * v; }
#pragma unroll
    for (int off = 1; off <= 8; off <<= 1) { s += __shfl_xor(s, off, 64); sq += __shfl_xor(sq, off, 64); }
    float mean = s * (1.f / 96.f);
    float var = sq * (1.f / 96.f) - mean * mean;
    float rs = rsqrtf(var + 1e-5f);
#pragma unroll
    for (int nt = 0; nt < 6; ++nt) xn[r][nt] = (xv[r][nt] - mean) * rs * gv[nt] + bv[nt];
  }
#pragma unroll
  for (int r = 0; r < 4; ++r) {
    int mm = lrow * 4 + r;
#pragma unroll
    for (int nt = 0; nt < 6; ++nt) {
      int c = nt * 16 + lcol;
      int kt = c >> 5;
      int lanew = mm + (((c & 31) >> 3) << 4);
      sm0[((w * 3 + kt) * 64 + lanew) * 8 + (c & 7)] = f2bf(xn[r][nt]);
    }
  }
  __syncthreads();

  // ---- phase 1: QKV GEMM. q/k: swapped MFMA (D=[ch][tok]) -> b64 stores.
  //      v: normal (D=[tok][ch], 4 consecutive tokens/lane) -> b64 stores.
  bf16x8 af[3];
#pragma unroll
  for (int kt = 0; kt < 3; ++kt) af[kt] = *(const bf16x8*)(sm0 + ((w * 3 + kt) * 64 + lane) * 8);
  for (int nt = 0; nt < 18; ++nt) {
    f32x4 acc = {0.f, 0.f, 0.f, 0.f};
    if (nt < 12) {
#pragma unroll
      for (int kt = 0; kt < 3; ++kt) {
        int tile = (nt < 6) ? (WQ_T + kt * 6 + nt) : (WKV_T + kt * 12 + (nt - 6));
        acc = MFMA(ldw(wswz, tile, lane), af[kt], acc);
      }
      if (nt < 6) {                       // q: scale+bias, channels cq..cq+3
        int cq = nt * 16 + lrow * 4;
        f32x4 b4 = *(const f32x4*)(bq + cq);
        int head = cq >> 5, d0 = cq & 31;
        unsigned p0 = cvtpk_bf16((acc.x + b4.x) * 0.17677669529663687f,
                                 (acc.y + b4.y) * 0.17677669529663687f);
        unsigned p1 = cvtpk_bf16((acc.z + b4.z) * 0.17677669529663687f,
                                 (acc.w + b4.w) * 0.17677669529663687f);
        uint2 uv = {p0, p1};
        *(uint2*)(sm1 + (((head * 4 + w) * 64) + lcol + ((d0 >> 3) << 4)) * 8 + (d0 & 7)) = uv;
      } else {                            // k
        int ck = (nt - 6) * 16 + lrow * 4;
        f32x4 b4 = *(const f32x4*)(bkv + ck);
        int head = ck >> 5, d0 = ck & 31;
        unsigned p0 = cvtpk_bf16(acc.x + b4.x, acc.y + b4.y);
        unsigned p1 = cvtpk_bf16(acc.z + b4.z, acc.w + b4.w);
        uint2 uv = {p0, p1};
        *(uint2*)(sm1 + ((12 + head * 4 + w) * 64 + lcol + ((d0 >> 3) << 4)) * 8 + (d0 & 7)) = uv;
      }
    } else {                              // v: normal orientation
#pragma unroll
      for (int kt = 0; kt < 3; ++kt)
        acc = MFMA(af[kt], ldw(wswz, WKV_T + kt * 12 + (nt - 6), lane), acc);
      int vc = (nt - 12) * 16 + lcol;
      float bvv = bkv[96 + vc];
      int head = vc >> 5, nt2 = (vc >> 4) & 1;
      int m0 = w * 16 + lrow * 4;
      unsigned p0 = cvtpk_bf16(acc.x + bvv, acc.y + bvv);
      unsigned p1 = cvtpk_bf16(acc.z + bvv, acc.w + bvv);
      uint2 uv = {p0, p1};
      *(uint2*)(sm2 + ((((head * 2 + (m0 >> 5)) * 2 + nt2) * 64) + lcol +
                       (((m0 & 31) >> 3) << 4)) * 8 + (m0 & 7)) = uv;
    }
  }
  __syncthreads();

  // ---- phase 2: scores. unit u=(head,mtq); wave w owns u = 3w..3w+2
  f32x4 sc[3][4];
#pragma unroll
  for (int uu = 0; uu < 3; ++uu) {
    int u = w * 3 + uu, head = u >> 2, mtq = u & 3;
    bf16x8 aq = *(const bf16x8*)(sm1 + ((head * 4 + mtq) * 64 + lane) * 8);
#pragma unroll
    for (int nt = 0; nt < 4; ++nt) {
      bf16x8 bk = *(const bf16x8*)(sm1 + ((12 + head * 4 + nt) * 64 + lane) * 8);
      f32x4 z = {0.f, 0.f, 0.f, 0.f};
      sc[uu][nt] = MFMA(aq, bk, z);
    }
  }
  __syncthreads();   // all q/k reads done; sm1 may now be overwritten with P

  // ---- phase 3: +rpb bias, softmax (in-register), write P to A-swz LDS
#pragma unroll
  for (int uu = 0; uu < 3; ++uu) {
    int u = w * 3 + uu, head = u >> 2, mtq = u & 3;
#pragma unroll
    for (int nt = 0; nt < 4; ++nt) {
      int ktok = nt * 16 + lcol;
#pragma unroll
      for (int r = 0; r < 4; ++r) {
        int qtok = mtq * 16 + lrow * 4 + r;
        int dy = (qtok >> 3) - (ktok >> 3) + 7;
        int dx = (qtok & 7) - (ktok & 7) + 7;
        sc[uu][nt][r] += rpb[(dy * 15 + dx) * 3 + head];
      }
    }
#pragma unroll
    for (int r = 0; r < 4; ++r) {
      float mx = fmaxf(fmaxf(sc[uu][0][r], sc[uu][1][r]), fmaxf(sc[uu][2][r], sc[uu][3][r]));
#pragma unroll
      for (int off = 1; off <= 8; off <<= 1) mx = fmaxf(mx, __shfl_xor(mx, off, 64));
      float p[4], sum = 0.f;
#pragma unroll
      for (int nt = 0; nt < 4; ++nt) { p[nt] = __expf(sc[uu][nt][r] - mx); sum += p[nt]; }
#pragma unroll
      for (int off = 1; off <= 8; off <<= 1) sum += __shfl_xor(sum, off, 64);
      float inv = 1.f / sum;
#pragma unroll
      for (int nt = 0; nt < 4; ++nt) sc[uu][nt][r] = p[nt] * inv;
    }
#pragma unroll
    for (int nt = 0; nt < 4; ++nt) {
      int ktok = nt * 16 + lcol;
      int ktile = ktok >> 5, lhi = (ktok & 31) >> 3;
#pragma unroll
      for (int r = 0; r < 4; ++r) {
        int mm = lrow * 4 + r;
        sm1[(((head * 4 + mtq) * 2 + ktile) * 64 + mm + (lhi << 4)) * 8 + (ktok & 7)] = f2bf(sc[uu][nt][r]);
      }
    }
  }
  __syncthreads();

  // ---- phase 4: PV, write y to A-swz LDS (reuse sm0; head = k-tile)
#pragma unroll
  for (int uu = 0; uu < 3; ++uu) {
    int u = w * 3 + uu, head = u >> 2, mtq = u & 3;
#pragma unroll
    for (int nt2 = 0; nt2 < 2; ++nt2) {
      f32x4 acc = {0.f, 0.f, 0.f, 0.f};
#pragma unroll
      for (int ktile = 0; ktile < 2; ++ktile) {
        bf16x8 ap = *(const bf16x8*)(sm1 + (((head * 4 + mtq) * 2 + ktile) * 64 + lane) * 8);
        bf16x8 bv8 = *(const bf16x8*)(sm2 + (((head * 2 + ktile) * 2 + nt2) * 64 + lane) * 8);
        acc = MFMA(ap, bv8, acc);
      }
      int d0 = nt2 * 16 + lcol;
#pragma unroll
      for (int r = 0; r < 4; ++r) {
        int mm = lrow * 4 + r;
        sm0[((mtq * 3 + head) * 64 + mm + ((d0 >> 3) << 4)) * 8 + (d0 & 7)] = f2bf(acc[r]);
      }
    }
  }
  __syncthreads();

  // ---- phase 5: proj + bias + residual -> x2
  bf16x8 ay[3];
#pragma unroll
  for (int kt = 0; kt < 3; ++kt) ay[kt] = *(const bf16x8*)(sm0 + ((w * 3 + kt) * 64 + lane) * 8);
#pragma unroll
  for (int nt = 0; nt < 6; ++nt) {
    f32x4 acc = {0.f, 0.f, 0.f, 0.f};
#pragma unroll
    for (int kt = 0; kt < 3; ++kt) acc = MFMA(ay[kt], ldw(wswz, WP_T + kt * 6 + nt, lane), acc);
    int c = nt * 16 + lcol;
    float bpc = bp[c];
#pragma unroll
    for (int r = 0; r < 4; ++r) x2[rowoff[r] + c] = acc[r] + bpc + xv[r][nt];
  }
}

// ---------------- FUSED LeFF: LN2+FC1+GELU+dwconv+GELU+FC2+residual --------
// Halves (192 ch). h: bf16 [100 halo-tokens][200 (192ch + pad8)] = 40KB.
// FC1 swapped -> per-lane 4 consecutive channels -> b64 stores (no scatter).
// Conv reads 8ch b128 per tap; dw weights/bias stream from L1.
__device__ __forceinline__ bf16x8 dwconv_gelu_g(
    const unsigned short* h00,                    // LDS ptr at tap (0,0)
    const float* __restrict__ wdwT, const float* __restrict__ bdw, int ch) {
  f32x2 a2[4];
#pragma unroll
  for (int j = 0; j < 4; ++j) a2[j] = (f32x2){0.f, 0.f};
#pragma unroll
  for (int dy = 0; dy < 3; ++dy) {
    uint4 dv[3];
#pragma unroll
    for (int dx = 0; dx < 3; ++dx)
      dv[dx] = *(const uint4*)(h00 + (dy * 10 + dx) * 200);
#pragma unroll
    for (int dx = 0; dx < 3; ++dx) {
      int t = dy * 3 + dx;
      f32x4 wlo = *(const f32x4*)(wdwT + t * 384 + ch);
      f32x4 whi = *(const f32x4*)(wdwT + t * 384 + ch + 4);
      const unsigned* du = (const unsigned*)&dv[dx];
      f32x2 d0 = { asf(du[0] << 16), asf(du[0] & 0xffff0000u) };
      f32x2 d1 = { asf(du[1] << 16), asf(du[1] & 0xffff0000u) };
      f32x2 d2 = { asf(du[2] << 16), asf(du[2] & 0xffff0000u) };
      f32x2 d3 = { asf(du[3] << 16), asf(du[3] & 0xffff0000u) };
      f32x2 w0 = {wlo.x, wlo.y}, w1 = {wlo.z, wlo.w};
      f32x2 w2v = {whi.x, whi.y}, w3 = {whi.z, whi.w};
      a2[0] += d0 * w0; a2[1] += d1 * w1; a2[2] += d2 * w2v; a2[3] += d3 * w3;
    }
  }
  f32x4 blo = *(const f32x4*)(bdw + ch);
  f32x4 bhi = *(const f32x4*)(bdw + ch + 4);
  union { unsigned u[4]; bf16x8 v; } pk;
  pk.u[0] = cvtpk_bf16(gelu(a2[0].x + blo.x), gelu(a2[0].y + blo.y));
  pk.u[1] = cvtpk_bf16(gelu(a2[1].x + blo.z), gelu(a2[1].y + blo.w));
  pk.u[2] = cvtpk_bf16(gelu(a2[2].x + bhi.x), gelu(a2[2].y + bhi.y));
  pk.u[3] = cvtpk_bf16(gelu(a2[3].x + bhi.z), gelu(a2[3].y + bhi.w));
  return pk.v;
}

__global__ __launch_bounds__(256) void kleff(
    const float* __restrict__ x2, const float* __restrict__ g2,
    const float* __restrict__ b2, const float* __restrict__ bl1,
    const float* __restrict__ wdwT, const float* __restrict__ bdw,
    const float* __restrict__ bl2, const unsigned short* __restrict__ wswz,
    float* __restrict__ out) {
  // h half-buffer [100][200] (40KB); phase-A xn A-frags (10752 u16) alias it
  __shared__ __align__(16) unsigned short smem[100 * 200];

  const int tid = threadIdx.x, lane = tid & 63, w = tid >> 6;
  const int lrow = lane >> 4, lcol = lane & 15;
  const int bid = xcd_swz(blockIdx.x);
  const int b = bid >> 10, ty0 = ((bid >> 5) & 31) * 8, tx0 = (bid & 31) * 8;

  const int mt1 = (w < 3) ? 4 + w : 3;   // 7 m-tiles; w=3 duplicates tile 3

  // ---- phase A: LN2 over 10x10 halo tokens -> xn A-frag region of smem
  {
    float gv[6], bv[6];
#pragma unroll
    for (int nt = 0; nt < 6; ++nt) { gv[nt] = g2[nt * 16 + lcol]; bv[nt] = b2[nt * 16 + lcol]; }
#pragma unroll
    for (int mi = 0; mi < 2; ++mi) {
      const int mt = mi ? mt1 : w;
      float xv[4][6];
#pragma unroll
      for (int r = 0; r < 4; ++r) {
        int t = mt * 16 + lrow * 4 + r;
        int hy = (t * 205) >> 11, hx = t - hy * 10;     // t/10, t%10 for t<112
        int gy = ty0 - 1 + hy, gx = tx0 - 1 + hx;
        int cgy = min(max(gy, 0), 255), cgx = min(max(gx, 0), 255);
        long roff = ((long)b * 65536 + cgy * 256 + cgx) * 96;
#pragma unroll
        for (int nt = 0; nt < 6; ++nt) xv[r][nt] = x2[roff + nt * 16 + lcol];
      }
#pragma unroll
      for (int r = 0; r < 4; ++r) {
        float s = 0.f, sq = 0.f;
#pragma unroll
        for (int nt = 0; nt < 6; ++nt) { float v = xv[r][nt]; s += v; sq += v * v; }
#pragma unroll
        for (int off = 1; off <= 8; off <<= 1) { s += __shfl_xor(s, off, 64); sq += __shfl_xor(sq, off, 64); }
        float mean = s * (1.f / 96.f);
        float var = sq * (1.f / 96.f) - mean * mean;
        float rs = rsqrtf(var + 1e-5f);
        int mm = lrow * 4 + r;
#pragma unroll
        for (int nt = 0; nt < 6; ++nt) {
          float val = (xv[r][nt] - mean) * rs * gv[nt] + bv[nt];
          int c = nt * 16 + lcol;
          int kt = c >> 5;
          int lanew = mm + (((c & 31) >> 3) << 4);
          smem[((mt * 3 + kt) * 64 + lanew) * 8 + (c & 7)] = f2bf(val);
        }
      }
    }
  }
  __syncthreads();

  // A-frags for FC1 (both owned token-tiles) -> regs, then smem is reusable
  bf16x8 af0[3], af1[3];
#pragma unroll
  for (int kt = 0; kt < 3; ++kt) {
    af0[kt] = *(const bf16x8*)(smem + ((w * 3 + kt) * 64 + lane) * 8);
    af1[kt] = *(const bf16x8*)(smem + ((mt1 * 3 + kt) * 64 + lane) * 8);
  }
  __syncthreads();

  // per-lane token ids + validity for the swapped-FC1 stores
  const int tA = w * 16 + lcol;           // < 64, always stored
  const int tB = mt1 * 16 + lcol;         // may exceed 99
  bool okA, okB;
  {
    int hy = (tA * 205) >> 11, hx = tA - hy * 10;
    int gy = ty0 - 1 + hy, gx = tx0 - 1 + hx;
    okA = ((unsigned)gy < 256u) && ((unsigned)gx < 256u);
    hy = (tB * 205) >> 11; hx = tB - hy * 10;
    gy = ty0 - 1 + hy; gx = tx0 - 1 + hx;
    okB = ((unsigned)gy < 256u) && ((unsigned)gx < 256u) && (tB < 100);
  }
  const bool stB = (tB < 100);

  f32x4 acc[6];
#pragma unroll
  for (int nt = 0; nt < 6; ++nt) { f32x4 z = {0.f, 0.f, 0.f, 0.f}; acc[nt] = z; }

  const int pint = w * 16 + lcol;         // lane's interior pixel 0..63
  const int iy = pint >> 3, ix = pint & 7;

#pragma unroll
  for (int H = 0; H < 2; ++H) {
    // ---- FC1 half H (swapped MFMA): lane packs channels ct0..ct0+3 of one
    //      token; b64 store into h[t][ct0]; OOI tokens stored as zero.
#pragma unroll
    for (int ntl = 0; ntl < 12; ++ntl) {
      int nt = H * 12 + ntl;
      bf16x8 wf0 = ldw(wswz, W1_T + nt, lane);
      bf16x8 wf1 = ldw(wswz, W1_T + 24 + nt, lane);
      bf16x8 wf2 = ldw(wswz, W1_T + 48 + nt, lane);
      int ct0 = ntl * 16 + lrow * 4;                  // [0,192)
      f32x4 b4 = *(const f32x4*)(bl1 + H * 192 + ct0);
      f32x4 a0 = {0.f, 0.f, 0.f, 0.f}, a1 = {0.f, 0.f, 0.f, 0.f};
      a0 = MFMA(wf0, af0[0], a0); a0 = MFMA(wf1, af0[1], a0); a0 = MFMA(wf2, af0[2], a0);
      a1 = MFMA(wf0, af1[0], a1); a1 = MFMA(wf1, af1[1], a1); a1 = MFMA(wf2, af1[2], a1);
      unsigned p0 = cvtpk_bf16(gelu(a0.x + b4.x), gelu(a0.y + b4.y));
      unsigned p1 = cvtpk_bf16(gelu(a0.z + b4.z), gelu(a0.w + b4.w));
      uint2 uvA = { okA ? p0 : 0u, okA ? p1 : 0u };
      *(uint2*)(smem + tA * 200 + ct0) = uvA;
      unsigned q0 = cvtpk_bf16(gelu(a1.x + b4.x), gelu(a1.y + b4.y));
      unsigned q1 = cvtpk_bf16(gelu(a1.z + b4.z), gelu(a1.w + b4.w));
      if (stB) {
        uint2 uvB = { okB ? q0 : 0u, okB ? q1 : 0u };
        *(uint2*)(smem + tB * 200 + ct0) = uvB;
      }
    }
    __syncthreads();

    // ---- conv + FC2 half H: per-lane 9-tap b128 from h, weights from L1
#pragma unroll
    for (int ktl = 0; ktl < 6; ++ktl) {
      const int ktg = H * 6 + ktl;
      const int choff = ktl * 32 + lrow * 8;          // [0,192)
      const unsigned short* h00 = smem + (iy * 10 + ix) * 200 + choff;
      bf16x8 pk = dwconv_gelu_g(h00, wdwT, bdw, H * 192 + choff);
#pragma unroll
      for (int nt = 0; nt < 6; ++nt)
        acc[nt] = MFMA(pk, ldw(wswz, W2_T + ktg * 6 + nt, lane), acc[nt]);
    }
    __syncthreads();   // before next half overwrites h
  }

  // ---- epilogue: + bl2 + residual(x2) -> out (interior tokens)
#pragma unroll
  for (int nt = 0; nt < 6; ++nt) {
    int c = nt * 16 + lcol;
    float bb = bl2[c];
#pragma unroll
    for (int r = 0; r < 4; ++r) {
      int mm = w * 16 + lrow * 4 + r;
      int oy = ty0 + (mm >> 3), ox = tx0 + (mm & 7);
      long row = (long)b * 65536 + oy * 256 + ox;
      out[row * 96 + c] = acc[nt][r] + bb + x2[row * 96 + c];
    }
  }
}

// ---------------------------------------------------------------------------
extern "C" void kernel_launch(void* const* d_in, const int* in_sizes, int n_in,
                              void* d_out, int out_size, void* d_ws, size_t ws_size,
                              hipStream_t stream) {
  const float* x   = (const float*)d_in[0];
  const float* g1  = (const float*)d_in[1];
  const float* b1  = (const float*)d_in[2];
  const float* wq  = (const float*)d_in[3];
  const float* bq  = (const float*)d_in[4];
  const float* wkv = (const float*)d_in[5];
  const float* bkv = (const float*)d_in[6];
  const float* rpb = (const float*)d_in[7];
  const float* wp  = (const float*)d_in[8];
  const float* bp  = (const float*)d_in[9];
  const float* g2  = (const float*)d_in[10];
  const float* b2  = (const float*)d_in[11];
  const float* w1  = (const float*)d_in[12];
  const float* bl1 = (const float*)d_in[13];
  const float* wdw = (const float*)d_in[14];
  const float* bdw = (const float*)d_in[15];
  const float* w2  = (const float*)d_in[16];
  const float* bl2 = (const float*)d_in[17];

  char* ws = (char*)d_ws;
  unsigned short* wswz = (unsigned short*)ws;                      // 221 KB
  float* wdwT = (float*)(ws + (size_t)(256 << 10));                // 13.8 KB @256KB
  float* x2 = (float*)(ws + (size_t)(4 << 20));                    // 100.7 MB
  float* outp = (float*)d_out;

  kwconv<<<68, 256, 0, stream>>>(wq, wkv, wp, w1, w2, wdw, wswz, wdwT);
  kattn<<<4096, 256, 0, stream>>>(x, g1, b1, bq, bkv, rpb, bp, wswz, x2);
  kleff<<<4096, 256, 0, stream>>>(x2, g2, b2, bl1, wdwT, bdw, bl2, wswz, outp);
}

// Round 13
// 454.172 us; speedup vs baseline: 1.5597x; 1.0097x over previous
//
#include <hip/hip_runtime.h>
#include <math.h>

// ---------------------------------------------------------------------------
// Swin/Uformer block, MI355X. Sizes fixed: B=4 H=W=256 C=96 NH=3 HD=32 WIN=8
// N=64 HID=384. 3 kernels:
//   kwconv : f32 weights -> bf16 pre-swizzled B-frags; + wdw transposed f32
//   kattn  : LN1 + QKV + window-attn + proj + residual. Swapped MFMA
//            everywhere a scatter used to be: QKV q/k (D=[ch][tok]),
//            QK^T (D=[ktok][qtok], 2-shuffle softmax, b64 P-stores),
//            PV (D=[ch][qtok], b64 y-stores).
//   kleff  : FUSED LN2+FC1+GELU+dwconv3x3+GELU+FC2+residual, halves; FC1
//            swapped -> b64 h stores; phase-A LN paired (float2 + b32).
// MFMA 16x16x32 bf16 layouts used throughout:
//   A-frag: lane = (row%16) + 16*(k%32/8), elem = k%8   (rows = left operand)
//   B-frag: lane = (col%16) + 16*(k%32/8), elem = k%8
//   C/D   : row  = 4*(lane/16)+reg, col = lane%16
// Swapped trick: A/B frag index math is identical, so MFMA(Y,X) transposes
// D at zero data-movement cost; pick orientation so stores are b64-packable.
// ---------------------------------------------------------------------------

typedef __attribute__((ext_vector_type(8))) short bf16x8;
typedef __attribute__((ext_vector_type(4))) float f32x4;
typedef __attribute__((ext_vector_type(2))) float f32x2;

#define MFMA(a, b, c) __builtin_amdgcn_mfma_f32_16x16x32_bf16((a), (b), (c), 0, 0, 0)

#define WQ_T 0
#define WKV_T 18
#define WP_T 54
#define W1_T 72
#define W2_T 144
#define NTILES_TOT 216

__device__ __forceinline__ unsigned short f2bf(float f) {
  union { float f; unsigned u; } v; v.f = f;
  unsigned r = v.u + 0x7FFFu + ((v.u >> 16) & 1u);
  return (unsigned short)(r >> 16);
}
__device__ __forceinline__ float asf(unsigned u) {
  union { unsigned u; float f; } v; v.u = u; return v.f;
}
__device__ __forceinline__ unsigned cvtpk_bf16(float lo, float hi) {
  unsigned r;
  asm("v_cvt_pk_bf16_f32 %0, %1, %2" : "=v"(r) : "v"(lo), "v"(hi));
  return r;
}
// gelu(x) ~= x * sigmoid(1.702 x); max dev from erf-gelu ~0.02 (attenuated
// ~25x through FC2 sums); 6 VALU ops.
__device__ __forceinline__ float gelu(float x) {
  float a = __expf(-1.702f * x);
  return x * __builtin_amdgcn_rcpf(1.f + a);
}
__device__ __forceinline__ bf16x8 ldw(const unsigned short* wswz, int tile, int lane) {
  return *(const bf16x8*)(wswz + ((size_t)(tile * 64 + lane)) * 8);
}
__device__ __forceinline__ int xcd_swz(int bid) {   // 4096 % 8 == 0 -> bijective
  return (bid & 7) * 512 + (bid >> 3);
}

// --------------------------- weight convert/swizzle ------------------------
__global__ void kwconv(const float* __restrict__ wq, const float* __restrict__ wkv,
                       const float* __restrict__ wp, const float* __restrict__ w1,
                       const float* __restrict__ w2, const float* __restrict__ wdw,
                       unsigned short* __restrict__ wswz, float* __restrict__ wdwT) {
  int tid = blockIdx.x * 256 + threadIdx.x;
  if (tid >= NTILES_TOT * 64) {
    int i = tid - NTILES_TOT * 64;
    if (i < 3456) {                       // wdw (384,1,3,3) -> wdwT [tap][384]
      int ch = i % 384, tap = i / 384;
      wdwT[tap * 384 + ch] = wdw[ch * 9 + tap];
    }
    return;
  }
  int e = tid; const float* src; int N, NT;
  if (e < 1152)      { src = wq;  N = 96;  NT = 6; }
  else if (e < 3456) { src = wkv; N = 192; NT = 12; e -= 1152; }
  else if (e < 4608) { src = wp;  N = 96;  NT = 6;  e -= 3456; }
  else if (e < 9216) { src = w1;  N = 384; NT = 24; e -= 4608; }
  else               { src = w2;  N = 96;  NT = 6;  e -= 9216; }
  int lane = e & 63, t = e >> 6;
  int nt = t % NT, kt = t / NT;
  int k0 = kt * 32 + (lane >> 4) * 8;
  int n = nt * 16 + (lane & 15);
  unsigned short* dst = wswz + (size_t)tid * 8;
#pragma unroll
  for (int i = 0; i < 8; ++i) dst[i] = f2bf(src[(size_t)(k0 + i) * N + n]);
}

// --------------------------- attention block -------------------------------
__global__ __launch_bounds__(256) void kattn(
    const float* __restrict__ x, const float* __restrict__ g1, const float* __restrict__ b1,
    const float* __restrict__ bq, const float* __restrict__ bkv,
    const float* __restrict__ rpb, const float* __restrict__ bp,
    const unsigned short* __restrict__ wswz, float* __restrict__ x2) {
  __shared__ __align__(16) unsigned short sm0[4 * 3 * 64 * 8];   // xn_swz, later y_swz (12KB)
  __shared__ __align__(16) unsigned short sm1[24 * 64 * 8];      // q(12)+k(12) then p(24) (24KB)
  __shared__ __align__(16) unsigned short sm2[3 * 2 * 2 * 64 * 8]; // v (12KB)

  const int tid = threadIdx.x;
  const int lane = tid & 63, w = tid >> 6;
  const int lrow = lane >> 4, lcol = lane & 15;
  const int wi = xcd_swz(blockIdx.x);
  const int b = wi >> 10, wy = (wi >> 5) & 31, wx = wi & 31;

  long rowoff[4];
#pragma unroll
  for (int r = 0; r < 4; ++r) {
    int m = w * 16 + lrow * 4 + r;
    int gy = wy * 8 + (m >> 3), gx = wx * 8 + (m & 7);
    rowoff[r] = ((long)b * 65536 + gy * 256 + gx) * 96;
  }

  // ---- phase 0: load x (C/D-layout regs), LN1, write xn to A-swz LDS
  float xv[4][6], xn[4][6], gv[6], bv[6];
#pragma unroll
  for (int nt = 0; nt < 6; ++nt) {
    int c = nt * 16 + lcol;
    gv[nt] = g1[c]; bv[nt] = b1[c];
#pragma unroll
    for (int r = 0; r < 4; ++r) xv[r][nt] = x[rowoff[r] + c];
  }
#pragma unroll
  for (int r = 0; r < 4; ++r) {
    float s = 0.f, sq = 0.f;
#pragma unroll
    for (int nt = 0; nt < 6; ++nt) { float v = xv[r][nt]; s += v; sq += v * v; }
#pragma unroll
    for (int off = 1; off <= 8; off <<= 1) { s += __shfl_xor(s, off, 64); sq += __shfl_xor(sq, off, 64); }
    float mean = s * (1.f / 96.f);
    float var = sq * (1.f / 96.f) - mean * mean;
    float rs = rsqrtf(var + 1e-5f);
#pragma unroll
    for (int nt = 0; nt < 6; ++nt) xn[r][nt] = (xv[r][nt] - mean) * rs * gv[nt] + bv[nt];
  }
#pragma unroll
  for (int r = 0; r < 4; ++r) {
    int mm = lrow * 4 + r;
#pragma unroll
    for (int nt = 0; nt < 6; ++nt) {
      int c = nt * 16 + lcol;
      int kt = c >> 5;
      int lanew = mm + (((c & 31) >> 3) << 4);
      sm0[((w * 3 + kt) * 64 + lanew) * 8 + (c & 7)] = f2bf(xn[r][nt]);
    }
  }
  __syncthreads();

  // ---- phase 1: QKV GEMM. q/k: swapped MFMA (D=[ch][tok]) -> b64 stores.
  //      v: normal (D=[tok][ch], 4 consecutive tokens/lane) -> b64 stores.
  bf16x8 af[3];
#pragma unroll
  for (int kt = 0; kt < 3; ++kt) af[kt] = *(const bf16x8*)(sm0 + ((w * 3 + kt) * 64 + lane) * 8);
  for (int nt = 0; nt < 18; ++nt) {
    f32x4 acc = {0.f, 0.f, 0.f, 0.f};
    if (nt < 12) {
#pragma unroll
      for (int kt = 0; kt < 3; ++kt) {
        int tile = (nt < 6) ? (WQ_T + kt * 6 + nt) : (WKV_T + kt * 12 + (nt - 6));
        acc = MFMA(ldw(wswz, tile, lane), af[kt], acc);
      }
      if (nt < 6) {                       // q: scale+bias, channels cq..cq+3
        int cq = nt * 16 + lrow * 4;
        f32x4 b4 = *(const f32x4*)(bq + cq);
        int head = cq >> 5, d0 = cq & 31;
        unsigned p0 = cvtpk_bf16((acc.x + b4.x) * 0.17677669529663687f,
                                 (acc.y + b4.y) * 0.17677669529663687f);
        unsigned p1 = cvtpk_bf16((acc.z + b4.z) * 0.17677669529663687f,
                                 (acc.w + b4.w) * 0.17677669529663687f);
        uint2 uv = {p0, p1};
        *(uint2*)(sm1 + (((head * 4 + w) * 64) + lcol + ((d0 >> 3) << 4)) * 8 + (d0 & 7)) = uv;
      } else {                            // k
        int ck = (nt - 6) * 16 + lrow * 4;
        f32x4 b4 = *(const f32x4*)(bkv + ck);
        int head = ck >> 5, d0 = ck & 31;
        unsigned p0 = cvtpk_bf16(acc.x + b4.x, acc.y + b4.y);
        unsigned p1 = cvtpk_bf16(acc.z + b4.z, acc.w + b4.w);
        uint2 uv = {p0, p1};
        *(uint2*)(sm1 + ((12 + head * 4 + w) * 64 + lcol + ((d0 >> 3) << 4)) * 8 + (d0 & 7)) = uv;
      }
    } else {                              // v: normal orientation
#pragma unroll
      for (int kt = 0; kt < 3; ++kt)
        acc = MFMA(af[kt], ldw(wswz, WKV_T + kt * 12 + (nt - 6), lane), acc);
      int vc = (nt - 12) * 16 + lcol;
      float bvv = bkv[96 + vc];
      int head = vc >> 5, nt2 = (vc >> 4) & 1;
      int m0 = w * 16 + lrow * 4;
      unsigned p0 = cvtpk_bf16(acc.x + bvv, acc.y + bvv);
      unsigned p1 = cvtpk_bf16(acc.z + bvv, acc.w + bvv);
      uint2 uv = {p0, p1};
      *(uint2*)(sm2 + ((((head * 2 + (m0 >> 5)) * 2 + nt2) * 64) + lcol +
                       (((m0 & 31) >> 3) << 4)) * 8 + (m0 & 7)) = uv;
    }
  }
  __syncthreads();

  // ---- phase 2: scores, SWAPPED: sc = MFMA(K, Q) -> D[ktok][qtok].
  //      lane holds qtok = mtq*16+lcol, ktok = nt*16 + lrow*4 + r.
  f32x4 sc[3][4];
#pragma unroll
  for (int uu = 0; uu < 3; ++uu) {
    int u = w * 3 + uu, head = u >> 2, mtq = u & 3;
    bf16x8 aq = *(const bf16x8*)(sm1 + ((head * 4 + mtq) * 64 + lane) * 8);
#pragma unroll
    for (int nt = 0; nt < 4; ++nt) {
      bf16x8 bk = *(const bf16x8*)(sm1 + ((12 + head * 4 + nt) * 64 + lane) * 8);
      f32x4 z = {0.f, 0.f, 0.f, 0.f};
      sc[uu][nt] = MFMA(bk, aq, z);
    }
  }
  __syncthreads();   // all q/k reads done; sm1 may now be overwritten with P

  // ---- phase 3: +rpb, softmax over ktok (16 in-lane + 2 shuffles), b64 P
#pragma unroll
  for (int uu = 0; uu < 3; ++uu) {
    int u = w * 3 + uu, head = u >> 2, mtq = u & 3;
    const int qtok = mtq * 16 + lcol;
    const int qdy = (qtok >> 3), qdx = (qtok & 7);
#pragma unroll
    for (int nt = 0; nt < 4; ++nt) {
#pragma unroll
      for (int r = 0; r < 4; ++r) {
        int ktok = nt * 16 + lrow * 4 + r;
        int dy = qdy - (ktok >> 3) + 7;
        int dx = qdx - (ktok & 7) + 7;
        sc[uu][nt][r] += rpb[(dy * 15 + dx) * 3 + head];
      }
    }
    float mx = sc[uu][0][0];
#pragma unroll
    for (int nt = 0; nt < 4; ++nt)
#pragma unroll
      for (int r = 0; r < 4; ++r) mx = fmaxf(mx, sc[uu][nt][r]);
    mx = fmaxf(mx, __shfl_xor(mx, 16, 64));
    mx = fmaxf(mx, __shfl_xor(mx, 32, 64));
    float sum = 0.f;
#pragma unroll
    for (int nt = 0; nt < 4; ++nt)
#pragma unroll
      for (int r = 0; r < 4; ++r) { sc[uu][nt][r] = __expf(sc[uu][nt][r] - mx); sum += sc[uu][nt][r]; }
    sum += __shfl_xor(sum, 16, 64);
    sum += __shfl_xor(sum, 32, 64);
    float inv = 1.f / sum;
    const int ebase = (lrow & 1) * 4;
    const int hi = (lrow >> 1);
#pragma unroll
    for (int nt = 0; nt < 4; ++nt) {
      unsigned p0 = cvtpk_bf16(sc[uu][nt][0] * inv, sc[uu][nt][1] * inv);
      unsigned p1 = cvtpk_bf16(sc[uu][nt][2] * inv, sc[uu][nt][3] * inv);
      uint2 uv = {p0, p1};
      *(uint2*)(sm1 + ((((head * 4 + mtq) * 2 + (nt >> 1)) * 64) + lcol +
                       ((((nt & 1) * 2 + hi)) << 4)) * 8 + ebase) = uv;
    }
  }
  __syncthreads();

  // ---- phase 4: PV SWAPPED: D[vchan][qtok] -> b64 y stores into sm0
#pragma unroll
  for (int uu = 0; uu < 3; ++uu) {
    int u = w * 3 + uu, head = u >> 2, mtq = u & 3;
#pragma unroll
    for (int nt2 = 0; nt2 < 2; ++nt2) {
      f32x4 acc = {0.f, 0.f, 0.f, 0.f};
#pragma unroll
      for (int ktile = 0; ktile < 2; ++ktile) {
        bf16x8 ap = *(const bf16x8*)(sm1 + (((head * 4 + mtq) * 2 + ktile) * 64 + lane) * 8);
        bf16x8 bv8 = *(const bf16x8*)(sm2 + (((head * 2 + ktile) * 2 + nt2) * 64 + lane) * 8);
        acc = MFMA(bv8, ap, acc);
      }
      // lane: qtok col = lcol (tile mtq); vchan d = nt2*16 + lrow*4 + r
      unsigned p0 = cvtpk_bf16(acc.x, acc.y);
      unsigned p1 = cvtpk_bf16(acc.z, acc.w);
      uint2 uv = {p0, p1};
      *(uint2*)(sm0 + ((mtq * 3 + head) * 64 + lcol +
                       ((nt2 * 2 + (lrow >> 1)) << 4)) * 8 + (lrow & 1) * 4) = uv;
    }
  }
  __syncthreads();

  // ---- phase 5: proj + bias + residual -> x2
  bf16x8 ay[3];
#pragma unroll
  for (int kt = 0; kt < 3; ++kt) ay[kt] = *(const bf16x8*)(sm0 + ((w * 3 + kt) * 64 + lane) * 8);
#pragma unroll
  for (int nt = 0; nt < 6; ++nt) {
    f32x4 acc = {0.f, 0.f, 0.f, 0.f};
#pragma unroll
    for (int kt = 0; kt < 3; ++kt) acc = MFMA(ay[kt], ldw(wswz, WP_T + kt * 6 + nt, lane), acc);
    int c = nt * 16 + lcol;
    float bpc = bp[c];
#pragma unroll
    for (int r = 0; r < 4; ++r) x2[rowoff[r] + c] = acc[r] + bpc + xv[r][nt];
  }
}

// ---------------- FUSED LeFF: LN2+FC1+GELU+dwconv+GELU+FC2+residual --------
// Halves (192 ch). h: bf16 [100 halo-tokens][200 (192ch + pad8)] = 40KB.
// FC1 swapped -> per-lane 4 consecutive channels -> b64 stores (no scatter).
// Conv reads 8ch b128 per tap; dw weights/bias stream from L1.
__device__ __forceinline__ bf16x8 dwconv_gelu_g(
    const unsigned short* h00,                    // LDS ptr at tap (0,0)
    const float* __restrict__ wdwT, const float* __restrict__ bdw, int ch) {
  f32x2 a2[4];
#pragma unroll
  for (int j = 0; j < 4; ++j) a2[j] = (f32x2){0.f, 0.f};
#pragma unroll
  for (int dy = 0; dy < 3; ++dy) {
    uint4 dv[3];
#pragma unroll
    for (int dx = 0; dx < 3; ++dx)
      dv[dx] = *(const uint4*)(h00 + (dy * 10 + dx) * 200);
#pragma unroll
    for (int dx = 0; dx < 3; ++dx) {
      int t = dy * 3 + dx;
      f32x4 wlo = *(const f32x4*)(wdwT + t * 384 + ch);
      f32x4 whi = *(const f32x4*)(wdwT + t * 384 + ch + 4);
      const unsigned* du = (const unsigned*)&dv[dx];
      f32x2 d0 = { asf(du[0] << 16), asf(du[0] & 0xffff0000u) };
      f32x2 d1 = { asf(du[1] << 16), asf(du[1] & 0xffff0000u) };
      f32x2 d2 = { asf(du[2] << 16), asf(du[2] & 0xffff0000u) };
      f32x2 d3 = { asf(du[3] << 16), asf(du[3] & 0xffff0000u) };
      f32x2 w0 = {wlo.x, wlo.y}, w1 = {wlo.z, wlo.w};
      f32x2 w2v = {whi.x, whi.y}, w3 = {whi.z, whi.w};
      a2[0] += d0 * w0; a2[1] += d1 * w1; a2[2] += d2 * w2v; a2[3] += d3 * w3;
    }
  }
  f32x4 blo = *(const f32x4*)(bdw + ch);
  f32x4 bhi = *(const f32x4*)(bdw + ch + 4);
  union { unsigned u[4]; bf16x8 v; } pk;
  pk.u[0] = cvtpk_bf16(gelu(a2[0].x + blo.x), gelu(a2[0].y + blo.y));
  pk.u[1] = cvtpk_bf16(gelu(a2[1].x + blo.z), gelu(a2[1].y + blo.w));
  pk.u[2] = cvtpk_bf16(gelu(a2[2].x + bhi.x), gelu(a2[2].y + bhi.y));
  pk.u[3] = cvtpk_bf16(gelu(a2[3].x + bhi.z), gelu(a2[3].y + bhi.w));
  return pk.v;
}

__global__ __launch_bounds__(256) void kleff(
    const float* __restrict__ x2, const float* __restrict__ g2,
    const float* __restrict__ b2, const float* __restrict__ bl1,
    const float* __restrict__ wdwT, const float* __restrict__ bdw,
    const float* __restrict__ bl2, const unsigned short* __restrict__ wswz,
    float* __restrict__ out) {
  // h half-buffer [100][200] (40KB); phase-A xn A-frags (10752 u16) alias it
  __shared__ __align__(16) unsigned short smem[100 * 200];

  const int tid = threadIdx.x, lane = tid & 63, w = tid >> 6;
  const int lrow = lane >> 4, lcol = lane & 15;
  const int bid = xcd_swz(blockIdx.x);
  const int b = bid >> 10, ty0 = ((bid >> 5) & 31) * 8, tx0 = (bid & 31) * 8;

  const int mt1 = (w < 3) ? 4 + w : 3;   // 7 m-tiles; w=3 duplicates tile 3

  // ---- phase A: LN2 over 10x10 halo tokens (paired float2) -> xn A-frags
  {
    float2 gv2[3], bv2[3];
#pragma unroll
    for (int n3 = 0; n3 < 3; ++n3) {
      gv2[n3] = *(const float2*)(g2 + n3 * 32 + lcol * 2);
      bv2[n3] = *(const float2*)(b2 + n3 * 32 + lcol * 2);
    }
#pragma unroll
    for (int mi = 0; mi < 2; ++mi) {
      const int mt = mi ? mt1 : w;
      float2 xv[4][3];
#pragma unroll
      for (int r = 0; r < 4; ++r) {
        int t = mt * 16 + lrow * 4 + r;
        int hy = (t * 205) >> 11, hx = t - hy * 10;     // t/10, t%10 for t<112
        int gy = ty0 - 1 + hy, gx = tx0 - 1 + hx;
        int cgy = min(max(gy, 0), 255), cgx = min(max(gx, 0), 255);
        long roff = ((long)b * 65536 + cgy * 256 + cgx) * 96;
#pragma unroll
        for (int n3 = 0; n3 < 3; ++n3)
          xv[r][n3] = *(const float2*)(x2 + roff + n3 * 32 + lcol * 2);
      }
#pragma unroll
      for (int r = 0; r < 4; ++r) {
        float s = 0.f, sq = 0.f;
#pragma unroll
        for (int n3 = 0; n3 < 3; ++n3) {
          float2 v = xv[r][n3];
          s += v.x + v.y; sq += v.x * v.x + v.y * v.y;
        }
#pragma unroll
        for (int off = 1; off <= 8; off <<= 1) { s += __shfl_xor(s, off, 64); sq += __shfl_xor(sq, off, 64); }
        float mean = s * (1.f / 96.f);
        float var = sq * (1.f / 96.f) - mean * mean;
        float rs = rsqrtf(var + 1e-5f);
        int mm = lrow * 4 + r;
#pragma unroll
        for (int n3 = 0; n3 < 3; ++n3) {
          float vx = (xv[r][n3].x - mean) * rs * gv2[n3].x + bv2[n3].x;
          float vy = (xv[r][n3].y - mean) * rs * gv2[n3].y + bv2[n3].y;
          // c = n3*32 + lcol*2 ; kt = n3 ; granule hi = lcol>>2 ; elem = c&7
          unsigned pk = cvtpk_bf16(vx, vy);
          *(unsigned*)(smem + ((mt * 3 + n3) * 64 + mm + ((lcol >> 2) << 4)) * 8 +
                       ((lcol * 2) & 7)) = pk;
        }
      }
    }
  }
  __syncthreads();

  // A-frags for FC1 (both owned token-tiles) -> regs, then smem is reusable
  bf16x8 af0[3], af1[3];
#pragma unroll
  for (int kt = 0; kt < 3; ++kt) {
    af0[kt] = *(const bf16x8*)(smem + ((w * 3 + kt) * 64 + lane) * 8);
    af1[kt] = *(const bf16x8*)(smem + ((mt1 * 3 + kt) * 64 + lane) * 8);
  }
  __syncthreads();

  // per-lane token ids + validity for the swapped-FC1 stores
  const int tA = w * 16 + lcol;           // < 64, always stored
  const int tB = mt1 * 16 + lcol;         // may exceed 99
  bool okA, okB;
  {
    int hy = (tA * 205) >> 11, hx = tA - hy * 10;
    int gy = ty0 - 1 + hy, gx = tx0 - 1 + hx;
    okA = ((unsigned)gy < 256u) && ((unsigned)gx < 256u);
    hy = (tB * 205) >> 11; hx = tB - hy * 10;
    gy = ty0 - 1 + hy; gx = tx0 - 1 + hx;
    okB = ((unsigned)gy < 256u) && ((unsigned)gx < 256u) && (tB < 100);
  }
  const bool stB = (tB < 100);

  f32x4 acc[6];
#pragma unroll
  for (int nt = 0; nt < 6; ++nt) { f32x4 z = {0.f, 0.f, 0.f, 0.f}; acc[nt] = z; }

  const int pint = w * 16 + lcol;         // lane's interior pixel 0..63
  const int iy = pint >> 3, ix = pint & 7;

#pragma unroll
  for (int H = 0; H < 2; ++H) {
    // ---- FC1 half H (swapped MFMA): lane packs channels ct0..ct0+3 of one
    //      token; b64 store into h[t][ct0]; OOI tokens stored as zero.
#pragma unroll
    for (int ntl = 0; ntl < 12; ++ntl) {
      int nt = H * 12 + ntl;
      bf16x8 wf0 = ldw(wswz, W1_T + nt, lane);
      bf16x8 wf1 = ldw(wswz, W1_T + 24 + nt, lane);
      bf16x8 wf2 = ldw(wswz, W1_T + 48 + nt, lane);
      int ct0 = ntl * 16 + lrow * 4;                  // [0,192)
      f32x4 b4 = *(const f32x4*)(bl1 + H * 192 + ct0);
      f32x4 a0 = {0.f, 0.f, 0.f, 0.f}, a1 = {0.f, 0.f, 0.f, 0.f};
      a0 = MFMA(wf0, af0[0], a0); a0 = MFMA(wf1, af0[1], a0); a0 = MFMA(wf2, af0[2], a0);
      a1 = MFMA(wf0, af1[0], a1); a1 = MFMA(wf1, af1[1], a1); a1 = MFMA(wf2, af1[2], a1);
      unsigned p0 = cvtpk_bf16(gelu(a0.x + b4.x), gelu(a0.y + b4.y));
      unsigned p1 = cvtpk_bf16(gelu(a0.z + b4.z), gelu(a0.w + b4.w));
      uint2 uvA = { okA ? p0 : 0u, okA ? p1 : 0u };
      *(uint2*)(smem + tA * 200 + ct0) = uvA;
      unsigned q0 = cvtpk_bf16(gelu(a1.x + b4.x), gelu(a1.y + b4.y));
      unsigned q1 = cvtpk_bf16(gelu(a1.z + b4.z), gelu(a1.w + b4.w));
      if (stB) {
        uint2 uvB = { okB ? q0 : 0u, okB ? q1 : 0u };
        *(uint2*)(smem + tB * 200 + ct0) = uvB;
      }
    }
    __syncthreads();

    // ---- conv + FC2 half H: per-lane 9-tap b128 from h, weights from L1
#pragma unroll
    for (int ktl = 0; ktl < 6; ++ktl) {
      const int ktg = H * 6 + ktl;
      const int choff = ktl * 32 + lrow * 8;          // [0,192)
      const unsigned short* h00 = smem + (iy * 10 + ix) * 200 + choff;
      bf16x8 pk = dwconv_gelu_g(h00, wdwT, bdw, H * 192 + choff);
#pragma unroll
      for (int nt = 0; nt < 6; ++nt)
        acc[nt] = MFMA(pk, ldw(wswz, W2_T + ktg * 6 + nt, lane), acc[nt]);
    }
    __syncthreads();   // before next half overwrites h
  }

  // ---- epilogue: + bl2 + residual(x2) -> out (interior tokens)
#pragma unroll
  for (int nt = 0; nt < 6; ++nt) {
    int c = nt * 16 + lcol;
    float bb = bl2[c];
#pragma unroll
    for (int r = 0; r < 4; ++r) {
      int mm = w * 16 + lrow * 4 + r;
      int oy = ty0 + (mm >> 3), ox = tx0 + (mm & 7);
      long row = (long)b * 65536 + oy * 256 + ox;
      out[row * 96 + c] = acc[nt][r] + bb + x2[row * 96 + c];
    }
  }
}

// ---------------------------------------------------------------------------
extern "C" void kernel_launch(void* const* d_in, const int* in_sizes, int n_in,
                              void* d_out, int out_size, void* d_ws, size_t ws_size,
                              hipStream_t stream) {
  const float* x   = (const float*)d_in[0];
  const float* g1  = (const float*)d_in[1];
  const float* b1  = (const float*)d_in[2];
  const float* wq  = (const float*)d_in[3];
  const float* bq  = (const float*)d_in[4];
  const float* wkv = (const float*)d_in[5];
  const float* bkv = (const float*)d_in[6];
  const float* rpb = (const float*)d_in[7];
  const float* wp  = (const float*)d_in[8];
  const float* bp  = (const float*)d_in[9];
  const float* g2  = (const float*)d_in[10];
  const float* b2  = (const float*)d_in[11];
  const float* w1  = (const float*)d_in[12];
  const float* bl1 = (const float*)d_in[13];
  const float* wdw = (const float*)d_in[14];
  const float* bdw = (const float*)d_in[15];
  const float* w2  = (const float*)d_in[16];
  const float* bl2 = (const float*)d_in[17];

  char* ws = (char*)d_ws;
  unsigned short* wswz = (unsigned short*)ws;                      // 221 KB
  float* wdwT = (float*)(ws + (size_t)(256 << 10));                // 13.8 KB @256KB
  float* x2 = (float*)(ws + (size_t)(4 << 20));                    // 100.7 MB
  float* outp = (float*)d_out;

  kwconv<<<68, 256, 0, stream>>>(wq, wkv, wp, w1, w2, wdw, wswz, wdwT);
  kattn<<<4096, 256, 0, stream>>>(x, g1, b1, bq, bkv, rpb, bp, wswz, x2);
  kleff<<<4096, 256, 0, stream>>>(x2, g2, b2, bl1, wdwT, bdw, bl2, wswz, outp);
}